// Round 1
// baseline (2317.073 us; speedup 1.0000x reference)
//
#include <hip/hip_runtime.h>
#include <math.h>

#define NHEAD  16
#define DHEAD  64
#define DLAT   32
#define TSEQ   2048
#define NBATCH 2
#define CDIM   1024
#define MROWS  (NBATCH*TSEQ)   // 4096

// ---------------- GEMM: O[m][n] = sum_k X[m][k] * W[n][k] ----------------
// X: M x K row-major, W: N x K row-major, O: M x N row-major.
// 64x64 tile per 256-thread block, 4x4 micro-tile per thread, BK=16.
__global__ __launch_bounds__(256) void gemm_xwt(
        const float* __restrict__ X, const float* __restrict__ W,
        float* __restrict__ O, int M, int N, int K) {
    __shared__ float Xs[16][68];   // [k][m], pad 68 for bank spread
    __shared__ float Ws[16][68];   // [k][n]
    const int tid = threadIdx.x;
    const int bm = blockIdx.y * 64;
    const int bn = blockIdx.x * 64;
    const int ty = tid >> 4, tx = tid & 15;
    const int r0 = ty * 4, c0 = tx * 4;
    const int lrow = tid >> 2;          // 0..63
    const int lk   = (tid & 3) * 4;     // 0,4,8,12
    float acc[4][4] = {};
    const float* Xp = X + (size_t)(bm + lrow) * K + lk;
    const float* Wp = W + (size_t)(bn + lrow) * K + lk;
    for (int k0 = 0; k0 < K; k0 += 16) {
        float4 xa = *(const float4*)(Xp + k0);
        float4 wa = *(const float4*)(Wp + k0);
        __syncthreads();   // previous tile's compute must finish before overwrite
        Xs[lk+0][lrow] = xa.x; Xs[lk+1][lrow] = xa.y;
        Xs[lk+2][lrow] = xa.z; Xs[lk+3][lrow] = xa.w;
        Ws[lk+0][lrow] = wa.x; Ws[lk+1][lrow] = wa.y;
        Ws[lk+2][lrow] = wa.z; Ws[lk+3][lrow] = wa.w;
        __syncthreads();
        #pragma unroll
        for (int kk = 0; kk < 16; ++kk) {
            float4 a = *(const float4*)&Xs[kk][r0];
            float4 b = *(const float4*)&Ws[kk][c0];
            acc[0][0] += a.x*b.x; acc[0][1] += a.x*b.y; acc[0][2] += a.x*b.z; acc[0][3] += a.x*b.w;
            acc[1][0] += a.y*b.x; acc[1][1] += a.y*b.y; acc[1][2] += a.y*b.z; acc[1][3] += a.y*b.w;
            acc[2][0] += a.z*b.x; acc[2][1] += a.z*b.y; acc[2][2] += a.z*b.z; acc[2][3] += a.z*b.w;
            acc[3][0] += a.w*b.x; acc[3][1] += a.w*b.y; acc[3][2] += a.w*b.z; acc[3][3] += a.w*b.w;
        }
    }
    #pragma unroll
    for (int i = 0; i < 4; ++i) {
        float4 o = make_float4(acc[i][0], acc[i][1], acc[i][2], acc[i][3]);
        *(float4*)&O[(size_t)(bm + r0 + i) * N + bn + c0] = o;
    }
}

// ---------------- Latent up-projection + RoPE ----------------
// k[b,h,t,d] = sum_l k_lat[b,t,h,l]*Wku[d,l]; same for v with Wvu.
// RoPE (interleaved pairs) on q and k. Emits (B,H,T,Dh); q pre-scaled by 1/8.
__global__ __launch_bounds__(256) void uprope(
        const float* __restrict__ qproj, const float* __restrict__ klat,
        const float* __restrict__ vlat, const float* __restrict__ Wku,
        const float* __restrict__ Wvu, float* __restrict__ qr,
        float* __restrict__ kr, float* __restrict__ vv) {
    const int g = blockIdx.x * 4 + (threadIdx.x >> 6);  // tuple over (b,t,h)
    const int d = threadIdx.x & 63;                     // lane == head dim
    const int h = g & (NHEAD - 1);
    const int bt = g >> 4;              // b*TSEQ + t
    const int t = bt & (TSEQ - 1);
    const int b = bt >> 11;
    const float* kl = klat + (size_t)bt * (NHEAD*DLAT) + h*DLAT;
    const float* vl = vlat + (size_t)bt * (NHEAD*DLAT) + h*DLAT;
    const float* wk = Wku + d*DLAT;
    const float* wv = Wvu + d*DLAT;
    float ka = 0.f, va = 0.f;
    #pragma unroll
    for (int l = 0; l < DLAT; ++l) {
        ka += kl[l] * wk[l];
        va += vl[l] * wv[l];
    }
    float qv = qproj[(size_t)bt * CDIM + h*DHEAD + d];
    // cos/sin(t * theta^{-(d mod 32)/32})
    float inv = powf(10000.f, -(float)(d & 31) * (1.0f/32.0f));
    float c, sn;
    sincosf((float)t * inv, &sn, &c);
    // even d: rot = -x[d+1]; odd d: rot = +x[d-1]  (partner via shfl_xor 1)
    float kp = __shfl_xor(ka, 1, 64);
    float qp = __shfl_xor(qv, 1, 64);
    float kro = ka * c + ((d & 1) ? kp : -kp) * sn;
    float qro = qv * c + ((d & 1) ? qp : -qp) * sn;
    size_t o = ((size_t)(b*NHEAD + h) * TSEQ + t) * DHEAD + d;
    qr[o] = qro * 0.125f;   // fold 1/sqrt(64) into q
    kr[o] = kro;
    vv[o] = va;
}

// ---------------- Flash attention (causal) ----------------
// One block = 64 query rows of one (b,h). 256 threads.
// Thread (r = tid>>2, g4 = tid&3): owns Q row r (in regs), S cols j=jj*4+g4,
// and acc slice d0 = g4*16 .. +15.
__global__ __launch_bounds__(256) void flash_attn(
        const float* __restrict__ qr, const float* __restrict__ kr,
        const float* __restrict__ vv, float* __restrict__ yatt) {
    const int qt = blockIdx.x;      // 0..31
    const int bh = blockIdx.y;      // 0..31
    const int b = bh >> 4, h = bh & 15;
    const float* Q = qr + ((size_t)bh * TSEQ + qt*64) * DHEAD;
    const float* K = kr + (size_t)bh * TSEQ * DHEAD;
    const float* V = vv + (size_t)bh * TSEQ * DHEAD;

    __shared__ float Ks[64][68];
    __shared__ float Vs[64][68];
    __shared__ float Ps[64][68];   // stages Q first, then holds P tiles

    const int tid = threadIdx.x;
    const int r  = tid >> 2;
    const int g4 = tid & 3;
    const int d0 = g4 * 16;
    const int lrow = tid >> 2;
    const int lc   = (tid & 3) * 4;

    // stage Q tile -> LDS -> regs
    {
        const float* Qt = Q + (size_t)lrow * DHEAD;
        #pragma unroll
        for (int i = 0; i < 4; ++i)
            *(float4*)&Ps[lrow][lc + i*16] = *(const float4*)(Qt + lc + i*16);
    }
    __syncthreads();
    float qreg[64];
    #pragma unroll
    for (int i = 0; i < 16; ++i) {
        float4 tq = *(const float4*)&Ps[r][i*4];
        qreg[i*4+0] = tq.x; qreg[i*4+1] = tq.y; qreg[i*4+2] = tq.z; qreg[i*4+3] = tq.w;
    }
    __syncthreads();

    float m_run = -1e30f, l_run = 0.f;
    float acc[16] = {};
    const int q_glob = qt*64 + r;

    for (int kt = 0; kt <= qt; ++kt) {
        // load K/V tile to regs, then LDS
        float4 kreg[4], vreg[4];
        const float* Kt = K + (size_t)(kt*64 + lrow) * DHEAD;
        const float* Vt = V + (size_t)(kt*64 + lrow) * DHEAD;
        #pragma unroll
        for (int i = 0; i < 4; ++i) {
            kreg[i] = *(const float4*)(Kt + lc + i*16);
            vreg[i] = *(const float4*)(Vt + lc + i*16);
        }
        __syncthreads();   // everyone done reading previous Ks/Vs/Ps
        #pragma unroll
        for (int i = 0; i < 4; ++i) {
            *(float4*)&Ks[lrow][lc + i*16] = kreg[i];
            *(float4*)&Vs[lrow][lc + i*16] = vreg[i];
        }
        __syncthreads();

        // S = Q K^T for this thread's 16 columns
        float s[16];
        #pragma unroll
        for (int jj = 0; jj < 16; ++jj) {
            const int j = jj*4 + g4;
            float sv = 0.f;
            const float* kp = &Ks[j][0];
            #pragma unroll
            for (int dd = 0; dd < 64; dd += 4) {
                float4 k4 = *(const float4*)(kp + dd);
                sv += qreg[dd]*k4.x + qreg[dd+1]*k4.y + qreg[dd+2]*k4.z + qreg[dd+3]*k4.w;
            }
            s[jj] = sv;
        }
        if (kt == qt) {
            #pragma unroll
            for (int jj = 0; jj < 16; ++jj) {
                if (kt*64 + jj*4 + g4 > q_glob) s[jj] = -1e30f;
            }
        }

        // online softmax (row reduction across the 4 lanes of this row)
        float mx = s[0];
        #pragma unroll
        for (int jj = 1; jj < 16; ++jj) mx = fmaxf(mx, s[jj]);
        mx = fmaxf(mx, __shfl_xor(mx, 1, 64));
        mx = fmaxf(mx, __shfl_xor(mx, 2, 64));
        float m_new = fmaxf(m_run, mx);
        float alpha = __expf(m_run - m_new);
        float p[16];
        float ls = 0.f;
        #pragma unroll
        for (int jj = 0; jj < 16; ++jj) { p[jj] = __expf(s[jj] - m_new); ls += p[jj]; }
        ls += __shfl_xor(ls, 1, 64);
        ls += __shfl_xor(ls, 2, 64);
        l_run = l_run * alpha + ls;
        m_run = m_new;

        #pragma unroll
        for (int jj = 0; jj < 16; ++jj) Ps[r][jj*4 + g4] = p[jj];
        __syncthreads();

        // acc = acc*alpha + P @ V  (thread's 16-wide d slice)
        #pragma unroll
        for (int i = 0; i < 16; ++i) acc[i] *= alpha;
        #pragma unroll 4
        for (int j = 0; j < 64; ++j) {
            float pj = Ps[r][j];
            float4 v0 = *(const float4*)&Vs[j][d0+0];
            float4 v1 = *(const float4*)&Vs[j][d0+4];
            float4 v2 = *(const float4*)&Vs[j][d0+8];
            float4 v3 = *(const float4*)&Vs[j][d0+12];
            acc[0] += pj*v0.x; acc[1] += pj*v0.y; acc[2]  += pj*v0.z; acc[3]  += pj*v0.w;
            acc[4] += pj*v1.x; acc[5] += pj*v1.y; acc[6]  += pj*v1.z; acc[7]  += pj*v1.w;
            acc[8] += pj*v2.x; acc[9] += pj*v2.y; acc[10] += pj*v2.z; acc[11] += pj*v2.w;
            acc[12]+= pj*v3.x; acc[13]+= pj*v3.y; acc[14] += pj*v3.z; acc[15] += pj*v3.w;
        }
    }

    // write y_att in (B, T, H*Dh) layout for the out-proj GEMM
    float invl = 1.0f / l_run;
    const int t = qt*64 + r;
    float* yp = yatt + ((size_t)b * TSEQ + t) * CDIM + h*DHEAD + d0;
    #pragma unroll
    for (int i = 0; i < 4; ++i) {
        float4 o = make_float4(acc[i*4+0]*invl, acc[i*4+1]*invl,
                               acc[i*4+2]*invl, acc[i*4+3]*invl);
        *(float4*)&yp[i*4] = o;
    }
}

extern "C" void kernel_launch(void* const* d_in, const int* in_sizes, int n_in,
                              void* d_out, int out_size, void* d_ws, size_t ws_size,
                              hipStream_t stream) {
    const float* x   = (const float*)d_in[0];
    const float* Wq  = (const float*)d_in[1];
    const float* Wk  = (const float*)d_in[2];
    const float* Wv  = (const float*)d_in[3];
    const float* Wku = (const float*)d_in[4];
    const float* Wvu = (const float*)d_in[5];
    const float* Wc  = (const float*)d_in[6];

    float* out_y  = (float*)d_out;                       // 4,194,304
    float* out_kl = out_y  + (size_t)MROWS * CDIM;       // 2,097,152
    float* out_vl = out_kl + (size_t)MROWS * NHEAD*DLAT; // 2,097,152

    float* ws    = (float*)d_ws;
    float* qproj = ws;                                   // (B,T,C)      16 MB
    float* qr    = ws + (size_t)MROWS * CDIM;            // (B,H,T,Dh)   16 MB
    float* kr    = qr + (size_t)MROWS * CDIM;            // (B,H,T,Dh)   16 MB
    float* vvp   = kr + (size_t)MROWS * CDIM;            // (B,H,T,Dh)   16 MB
    float* yatt  = qproj;  // alias: qproj dead after uprope

    // q/k_lat/v_lat projections (k_lat, v_lat go straight to d_out)
    gemm_xwt<<<dim3(CDIM/64,  MROWS/64), 256, 0, stream>>>(x, Wq, qproj, MROWS, CDIM, CDIM);
    gemm_xwt<<<dim3(512/64,   MROWS/64), 256, 0, stream>>>(x, Wk, out_kl, MROWS, 512, CDIM);
    gemm_xwt<<<dim3(512/64,   MROWS/64), 256, 0, stream>>>(x, Wv, out_vl, MROWS, 512, CDIM);

    // latent up-projection + RoPE -> (B,H,T,Dh)
    uprope<<<(MROWS*NHEAD)/4, 256, 0, stream>>>(qproj, out_kl, out_vl, Wku, Wvu, qr, kr, vvp);

    // causal flash attention -> y_att (B,T,C)
    flash_attn<<<dim3(TSEQ/64, NBATCH*NHEAD), 256, 0, stream>>>(qr, kr, vvp, yatt);

    // out projection
    gemm_xwt<<<dim3(CDIM/64, MROWS/64), 256, 0, stream>>>(yatt, Wc, out_y, MROWS, CDIM, CDIM);
}

// Round 2
// 717.336 us; speedup vs baseline: 3.2301x; 3.2301x over previous
//
#include <hip/hip_runtime.h>
#include <math.h>

#define NHEAD  16
#define DHEAD  64
#define DLAT   32
#define TSEQ   2048
#define NBATCH 2
#define CDIM   1024
#define MROWS  (NBATCH*TSEQ)   // 4096

typedef __attribute__((ext_vector_type(8))) short bf16x8;
typedef __attribute__((ext_vector_type(4))) float f32x4;

__device__ __forceinline__ unsigned short f2bf(float f) {
    union { float f; unsigned u; } v; v.f = f;
    unsigned r = v.u + 0x7fff + ((v.u >> 16) & 1);   // RNE
    return (unsigned short)(r >> 16);
}

// ---------------- GEMM: O[m][n] = sum_k X[m][k] * W[n][k] (fp32) ----------------
__global__ __launch_bounds__(256) void gemm_xwt(
        const float* __restrict__ X, const float* __restrict__ W,
        float* __restrict__ O, int M, int N, int K) {
    __shared__ float Xs[16][68];
    __shared__ float Ws[16][68];
    const int tid = threadIdx.x;
    const int bm = blockIdx.y * 64;
    const int bn = blockIdx.x * 64;
    const int ty = tid >> 4, tx = tid & 15;
    const int r0 = ty * 4, c0 = tx * 4;
    const int lrow = tid >> 2;
    const int lk   = (tid & 3) * 4;
    float acc[4][4] = {};
    const float* Xp = X + (size_t)(bm + lrow) * K + lk;
    const float* Wp = W + (size_t)(bn + lrow) * K + lk;
    for (int k0 = 0; k0 < K; k0 += 16) {
        float4 xa = *(const float4*)(Xp + k0);
        float4 wa = *(const float4*)(Wp + k0);
        __syncthreads();
        Xs[lk+0][lrow] = xa.x; Xs[lk+1][lrow] = xa.y;
        Xs[lk+2][lrow] = xa.z; Xs[lk+3][lrow] = xa.w;
        Ws[lk+0][lrow] = wa.x; Ws[lk+1][lrow] = wa.y;
        Ws[lk+2][lrow] = wa.z; Ws[lk+3][lrow] = wa.w;
        __syncthreads();
        #pragma unroll
        for (int kk = 0; kk < 16; ++kk) {
            float4 a = *(const float4*)&Xs[kk][r0];
            float4 b = *(const float4*)&Ws[kk][c0];
            acc[0][0] += a.x*b.x; acc[0][1] += a.x*b.y; acc[0][2] += a.x*b.z; acc[0][3] += a.x*b.w;
            acc[1][0] += a.y*b.x; acc[1][1] += a.y*b.y; acc[1][2] += a.y*b.z; acc[1][3] += a.y*b.w;
            acc[2][0] += a.z*b.x; acc[2][1] += a.z*b.y; acc[2][2] += a.z*b.z; acc[2][3] += a.z*b.w;
            acc[3][0] += a.w*b.x; acc[3][1] += a.w*b.y; acc[3][2] += a.w*b.z; acc[3][3] += a.w*b.w;
        }
    }
    #pragma unroll
    for (int i = 0; i < 4; ++i) {
        float4 o = make_float4(acc[i][0], acc[i][1], acc[i][2], acc[i][3]);
        *(float4*)&O[(size_t)(bm + r0 + i) * N + bn + c0] = o;
    }
}

// ---------------- Latent k up-projection + RoPE on q,k -> bf16 (b,h,t,d) ----------------
__global__ __launch_bounds__(256) void uprope(
        const float* __restrict__ qproj, const float* __restrict__ klat,
        const float* __restrict__ Wku,
        unsigned short* __restrict__ qb, unsigned short* __restrict__ kb) {
    const int g = blockIdx.x * 4 + (threadIdx.x >> 6);
    const int d = threadIdx.x & 63;
    const int h = g & (NHEAD - 1);
    const int bt = g >> 4;
    const int t = bt & (TSEQ - 1);
    const int b = bt >> 11;
    const float* kl = klat + (size_t)bt * (NHEAD*DLAT) + h*DLAT;
    const float* wk = Wku + d*DLAT;
    float ka = 0.f;
    #pragma unroll
    for (int l = 0; l < DLAT; ++l) ka += kl[l] * wk[l];
    float qv = qproj[(size_t)bt * CDIM + h*DHEAD + d];
    float inv = powf(10000.f, -(float)(d & 31) * (1.0f/32.0f));
    float c, sn;
    sincosf((float)t * inv, &sn, &c);
    float kp = __shfl_xor(ka, 1, 64);
    float qp = __shfl_xor(qv, 1, 64);
    float kro = ka * c + ((d & 1) ? kp : -kp) * sn;
    float qro = qv * c + ((d & 1) ? qp : -qp) * sn;
    size_t o = ((size_t)(b*NHEAD + h) * TSEQ + t) * DHEAD + d;
    qb[o] = f2bf(qro * 0.125f);   // fold 1/sqrt(64)
    kb[o] = f2bf(kro);
}

// ---------------- v up-projection -> bf16 V^T (b,h,d,t) ----------------
__global__ __launch_bounds__(256) void vup(
        const float* __restrict__ vlat, const float* __restrict__ Wvu,
        unsigned short* __restrict__ vt) {
    __shared__ float vs[64][33];
    const int bh = blockIdx.y;
    const int b = bh >> 4, h = bh & 15;
    const int t0 = blockIdx.x * 64;
    const int tid = threadIdx.x;
    {   // stage vlat tile (64 t x 32 l)
        const int r = tid >> 2, cs = (tid & 3) * 8;
        const float* src = vlat + ((size_t)(b*TSEQ + t0 + r)) * (NHEAD*DLAT) + h*DLAT + cs;
        *(float4*)&vs[r][cs]   = *(const float4*)src;
        *(float4*)&vs[r][cs+4] = *(const float4*)(src + 4);
    }
    __syncthreads();
    const int tl = tid & 63;
    const int dg = tid >> 6;           // wave-uniform -> Wvu reads go scalar
    float vrow[DLAT];
    #pragma unroll
    for (int l = 0; l < DLAT; ++l) vrow[l] = vs[tl][l];
    #pragma unroll
    for (int i = 0; i < 16; ++i) {
        const int d = dg*16 + i;
        float acc = 0.f;
        #pragma unroll
        for (int l = 0; l < DLAT; ++l) acc += vrow[l] * Wvu[d*DLAT + l];
        vt[((size_t)bh*DHEAD + d) * TSEQ + t0 + tl] = f2bf(acc);
    }
}

// ---------------- Flash attention, bf16 MFMA ----------------
// Block: 256 thr = 4 waves; Q tile 64 rows (16/wave), K tile 64.
// mfma_f32_16x16x32_bf16: C/D col=lane&15,row=quad*4+reg; A[m=lane&15][k=quad*8+j];
// B[k=quad*8+j][n=lane&15].
__global__ __launch_bounds__(256) void flash_attn(
        const unsigned short* __restrict__ qb, const unsigned short* __restrict__ kb,
        const unsigned short* __restrict__ vtb, float* __restrict__ yatt) {
    const int qt = gridDim.x - 1 - blockIdx.x;   // long blocks first
    const int bh = blockIdx.y;
    const int b = bh >> 4, h = bh & 15;

    __shared__ unsigned short Ks[64][72];    // K tile (t, d), +8 pad: 2-way bank alias only
    __shared__ unsigned short VTs[64][72];   // V^T tile (d, t_local)
    __shared__ unsigned short Ps[4][16][72]; // per-wave P round-trip

    const int tid  = threadIdx.x;
    const int wq   = tid >> 6;
    const int lane = tid & 63;
    const int quad = lane >> 4;
    const int l16  = lane & 15;

    // Q A-fragments, resident in regs
    const unsigned short* qbase =
        qb + ((size_t)bh*TSEQ + qt*64 + wq*16 + l16) * DHEAD + quad*8;
    bf16x8 qA0 = *(const bf16x8*)qbase;
    bf16x8 qA1 = *(const bf16x8*)(qbase + 32);

    f32x4 oacc[4] = {};   // d-chunks of O, C-layout
    float m_run[4], l_run[4];
    #pragma unroll
    for (int r = 0; r < 4; ++r) { m_run[r] = -1e30f; l_run[r] = 0.f; }

    const int row_loc = wq*16 + quad*4;      // + r
    const unsigned short* Kbase = kb  + (size_t)bh * TSEQ * DHEAD;
    const unsigned short* Vbase = vtb + (size_t)bh * DHEAD * TSEQ;

    for (int kt = 0; kt <= qt; ++kt) {
        __syncthreads();   // prev iter's LDS reads done
        #pragma unroll
        for (int i = 0; i < 2; ++i) {       // stage K and V^T tiles (8KB each)
            const int cid = tid + i*256;
            const int rr = cid >> 3, ss = (cid & 7) * 8;
            *(int4*)&Ks[rr][ss]  = *(const int4*)(Kbase + ((size_t)(kt*64 + rr))*DHEAD + ss);
            *(int4*)&VTs[rr][ss] = *(const int4*)(Vbase + (size_t)rr*TSEQ + kt*64 + ss);
        }
        __syncthreads();

        // S = Q K^T  (4 col-chunks of 16)
        f32x4 sacc[4];
        #pragma unroll
        for (int c = 0; c < 4; ++c) {
            bf16x8 b0 = *(const bf16x8*)&Ks[c*16 + l16][quad*8];
            bf16x8 b1 = *(const bf16x8*)&Ks[c*16 + l16][quad*8 + 32];
            f32x4 z = {0.f, 0.f, 0.f, 0.f};
            z = __builtin_amdgcn_mfma_f32_16x16x32_bf16(qA0, b0, z, 0, 0, 0);
            z = __builtin_amdgcn_mfma_f32_16x16x32_bf16(qA1, b1, z, 0, 0, 0);
            sacc[c] = z;
        }
        if (kt == qt) {  // causal mask (block-uniform branch)
            #pragma unroll
            for (int c = 0; c < 4; ++c)
                #pragma unroll
                for (int r = 0; r < 4; ++r)
                    if (c*16 + l16 > row_loc + r) sacc[c][r] = -1e30f;
        }

        // online softmax, per row r
        float mx[4];
        #pragma unroll
        for (int r = 0; r < 4; ++r) {
            mx[r] = fmaxf(fmaxf(sacc[0][r], sacc[1][r]), fmaxf(sacc[2][r], sacc[3][r]));
        }
        #pragma unroll
        for (int m = 1; m < 16; m <<= 1)
            #pragma unroll
            for (int r = 0; r < 4; ++r)
                mx[r] = fmaxf(mx[r], __shfl_xor(mx[r], m, 64));
        float al[4], ls[4];
        #pragma unroll
        for (int r = 0; r < 4; ++r) {
            float mn = fmaxf(m_run[r], mx[r]);
            al[r] = __expf(m_run[r] - mn);
            m_run[r] = mn;
            ls[r] = 0.f;
        }
        #pragma unroll
        for (int c = 0; c < 4; ++c)
            #pragma unroll
            for (int r = 0; r < 4; ++r) {
                float p = __expf(sacc[c][r] - m_run[r]);
                sacc[c][r] = p;
                ls[r] += p;
            }
        #pragma unroll
        for (int m = 1; m < 16; m <<= 1)
            #pragma unroll
            for (int r = 0; r < 4; ++r)
                ls[r] += __shfl_xor(ls[r], m, 64);
        #pragma unroll
        for (int r = 0; r < 4; ++r) l_run[r] = l_run[r]*al[r] + ls[r];
        #pragma unroll
        for (int c = 0; c < 4; ++c)
            #pragma unroll
            for (int r = 0; r < 4; ++r) oacc[c][r] *= al[r];

        // P: C-layout -> A-layout via per-wave LDS (same-wave, in-order DS pipe)
        #pragma unroll
        for (int c = 0; c < 4; ++c)
            #pragma unroll
            for (int r = 0; r < 4; ++r)
                Ps[wq][quad*4 + r][c*16 + l16] = f2bf(sacc[c][r]);
        bf16x8 aP0 = *(const bf16x8*)&Ps[wq][l16][quad*8];
        bf16x8 aP1 = *(const bf16x8*)&Ps[wq][l16][quad*8 + 32];

        // O += P V   (V^T staged: B[k=kcol][n=d] = VTs[d][kcol])
        #pragma unroll
        for (int c = 0; c < 4; ++c) {
            bf16x8 bv0 = *(const bf16x8*)&VTs[c*16 + l16][quad*8];
            bf16x8 bv1 = *(const bf16x8*)&VTs[c*16 + l16][quad*8 + 32];
            oacc[c] = __builtin_amdgcn_mfma_f32_16x16x32_bf16(aP0, bv0, oacc[c], 0, 0, 0);
            oacc[c] = __builtin_amdgcn_mfma_f32_16x16x32_bf16(aP1, bv1, oacc[c], 0, 0, 0);
        }
    }

    float invl[4];
    #pragma unroll
    for (int r = 0; r < 4; ++r) invl[r] = 1.0f / l_run[r];
    float* yp = yatt + ((size_t)(b*TSEQ) + qt*64 + row_loc) * CDIM + h*DHEAD;
    #pragma unroll
    for (int r = 0; r < 4; ++r)
        #pragma unroll
        for (int c = 0; c < 4; ++c)
            yp[(size_t)r*CDIM + c*16 + l16] = oacc[c][r] * invl[r];
}

extern "C" void kernel_launch(void* const* d_in, const int* in_sizes, int n_in,
                              void* d_out, int out_size, void* d_ws, size_t ws_size,
                              hipStream_t stream) {
    const float* x   = (const float*)d_in[0];
    const float* Wq  = (const float*)d_in[1];
    const float* Wk  = (const float*)d_in[2];
    const float* Wv  = (const float*)d_in[3];
    const float* Wku = (const float*)d_in[4];
    const float* Wvu = (const float*)d_in[5];
    const float* Wc  = (const float*)d_in[6];

    float* out_y  = (float*)d_out;
    float* out_kl = out_y  + (size_t)MROWS * CDIM;
    float* out_vl = out_kl + (size_t)MROWS * NHEAD*DLAT;

    float* ws    = (float*)d_ws;
    float* qproj = ws;                                        // fp32 (B,T,C)  16 MB
    unsigned short* qb = (unsigned short*)(ws + (size_t)MROWS*CDIM);        // bf16 8 MB
    unsigned short* kb = qb + (size_t)MROWS*CDIM;                            // bf16 8 MB
    unsigned short* vt = kb + (size_t)MROWS*CDIM;                            // bf16 8 MB
    float* yatt  = qproj;   // alias: qproj dead after uprope

    gemm_xwt<<<dim3(CDIM/64, MROWS/64), 256, 0, stream>>>(x, Wq, qproj, MROWS, CDIM, CDIM);
    gemm_xwt<<<dim3(512/64,  MROWS/64), 256, 0, stream>>>(x, Wk, out_kl, MROWS, 512, CDIM);
    gemm_xwt<<<dim3(512/64,  MROWS/64), 256, 0, stream>>>(x, Wv, out_vl, MROWS, 512, CDIM);

    uprope<<<(MROWS*NHEAD)/4, 256, 0, stream>>>(qproj, out_kl, Wku, qb, kb);
    vup<<<dim3(TSEQ/64, NBATCH*NHEAD), 256, 0, stream>>>(out_vl, Wvu, vt);

    flash_attn<<<dim3(TSEQ/64, NBATCH*NHEAD), 256, 0, stream>>>(qb, kb, vt, yatt);

    gemm_xwt<<<dim3(CDIM/64, MROWS/64), 256, 0, stream>>>(yatt, Wc, out_y, MROWS, CDIM, CDIM);
}

// Round 3
// 369.826 us; speedup vs baseline: 6.2653x; 1.9397x over previous
//
#include <hip/hip_runtime.h>
#include <math.h>

#define NHEAD  16
#define DHEAD  64
#define DLAT   32
#define TSEQ   2048
#define NBATCH 2
#define CDIM   1024
#define MROWS  (NBATCH*TSEQ)   // 4096

typedef __attribute__((ext_vector_type(8))) short bf16x8;
typedef __attribute__((ext_vector_type(4))) float f32x4;

#define AS1 __attribute__((address_space(1)))
#define AS3 __attribute__((address_space(3)))

__device__ __forceinline__ unsigned short f2bf(float f) {
    union { float f; unsigned u; } v; v.f = f;
    unsigned r = v.u + 0x7fff + ((v.u >> 16) & 1);   // RNE
    return (unsigned short)(r >> 16);
}

__device__ __forceinline__ void gld_lds16(const unsigned short* g, unsigned short* l) {
    // async global->LDS, 16B/lane; LDS dest = wave-uniform base + lane*16
    __builtin_amdgcn_global_load_lds((const AS1 void*)g, (AS3 void*)l, 16, 0, 0);
}

// ---------------- fp32 -> bf16 conversion ----------------
__global__ __launch_bounds__(256) void cvt_bf16(const float* __restrict__ src,
        unsigned short* __restrict__ dst, int n) {
    int i = (blockIdx.x * 256 + threadIdx.x) * 4;
    if (i < n) {
        float4 v = *(const float4*)(src + i);
        ushort4 o = { f2bf(v.x), f2bf(v.y), f2bf(v.z), f2bf(v.w) };
        *(ushort4*)(dst + i) = o;
    }
}

// ---------------- MFMA GEMM core: 128x128 tile, BK=32, 4 waves ----------------
// A: M x K bf16 row-major; W: N x K bf16 row-major; computes X*W^T 128x128 tile.
// Wave w owns 64x64 sub-tile (wm,wn); acc[t][c] is its 4x4 grid of 16x16 tiles.
__device__ __forceinline__ void gemm_core(
        const unsigned short* __restrict__ A, const unsigned short* __restrict__ W,
        int K, int bm, int bn, unsigned short* As, unsigned short* Bs,
        f32x4 (&acc)[4][4]) {
    const int tid = threadIdx.x;
    const int w = tid >> 6, lane = tid & 63;
    const int quad = lane >> 4, l16 = lane & 15;
    const int wm = (w >> 1) * 64, wn = (w & 1) * 64;

    const int lr = lane >> 2;          // staging row within 16-row group
    const int le = (lane & 3) * 8;     // staging element offset (8 bf16 = 16B)
    const unsigned short* Ag0 = A + (size_t)(bm + w*32 + lr) * K + le;
    const unsigned short* Wg0 = W + (size_t)(bn + w*32 + lr) * K + le;
    unsigned short* AsD0 = &As[(w*32 +  0) * 32];
    unsigned short* AsD1 = &As[(w*32 + 16) * 32];
    unsigned short* BsD0 = &Bs[(w*32 +  0) * 32];
    unsigned short* BsD1 = &Bs[(w*32 + 16) * 32];

    for (int k0 = 0; k0 < K; k0 += 32) {
        gld_lds16(Ag0 + k0,              AsD0);
        gld_lds16(Ag0 + k0 + (size_t)16*K, AsD1);
        gld_lds16(Wg0 + k0,              BsD0);
        gld_lds16(Wg0 + k0 + (size_t)16*K, BsD1);
        __syncthreads();   // drains vmcnt: LDS tiles ready
        bf16x8 af[4], bf[4];
        #pragma unroll
        for (int t = 0; t < 4; ++t)
            af[t] = *(const bf16x8*)&As[(wm + t*16 + l16)*32 + quad*8];
        #pragma unroll
        for (int c = 0; c < 4; ++c)
            bf[c] = *(const bf16x8*)&Bs[(wn + c*16 + l16)*32 + quad*8];
        #pragma unroll
        for (int t = 0; t < 4; ++t)
            #pragma unroll
            for (int c = 0; c < 4; ++c)
                acc[t][c] = __builtin_amdgcn_mfma_f32_16x16x32_bf16(af[t], bf[c], acc[t][c], 0, 0, 0);
        __syncthreads();   // reads done before next stage overwrites
    }
}

// Fused projection GEMM: A = x_bf16 (4096x1024), W = [Wq;Wk;Wv] (2048x1024).
// Epilogue routes cols: [0,1024)->qproj fp32, [1024,1536)->k_lat, [1536,2048)->v_lat.
__global__ __launch_bounds__(256) void gemm_proj(
        const unsigned short* __restrict__ A, const unsigned short* __restrict__ W,
        float* __restrict__ qproj, float* __restrict__ okl, float* __restrict__ ovl,
        int K) {
    __shared__ unsigned short As[128*32];
    __shared__ unsigned short Bs[128*32];
    const int bm = blockIdx.y * 128, bn = blockIdx.x * 128;
    f32x4 acc[4][4] = {};
    gemm_core(A, W, K, bm, bn, As, Bs, acc);

    const int tid = threadIdx.x;
    const int w = tid >> 6, lane = tid & 63;
    const int quad = lane >> 4, l16 = lane & 15;
    const int wm = (w >> 1) * 64, wn = (w & 1) * 64;

    float* base; int ldo;   // block-uniform routing (segment bounds are x128)
    if (bn < 1024)      { base = qproj + bn;        ldo = 1024; }
    else if (bn < 1536) { base = okl + (bn - 1024); ldo = 512;  }
    else                { base = ovl + (bn - 1536); ldo = 512;  }

    #pragma unroll
    for (int t = 0; t < 4; ++t)
        #pragma unroll
        for (int c = 0; c < 4; ++c)
            #pragma unroll
            for (int r = 0; r < 4; ++r) {
                int row = bm + wm + t*16 + quad*4 + r;
                int col = wn + c*16 + l16;
                base[(size_t)row * ldo + col] = acc[t][c][r];
            }
}

// Out-projection GEMM: A = yatt bf16 (4096x1024), W = Wc bf16 (1024x1024) -> fp32 y.
__global__ __launch_bounds__(256) void gemm_out(
        const unsigned short* __restrict__ A, const unsigned short* __restrict__ W,
        float* __restrict__ O, int N, int K) {
    __shared__ unsigned short As[128*32];
    __shared__ unsigned short Bs[128*32];
    const int bm = blockIdx.y * 128, bn = blockIdx.x * 128;
    f32x4 acc[4][4] = {};
    gemm_core(A, W, K, bm, bn, As, Bs, acc);

    const int tid = threadIdx.x;
    const int w = tid >> 6, lane = tid & 63;
    const int quad = lane >> 4, l16 = lane & 15;
    const int wm = (w >> 1) * 64, wn = (w & 1) * 64;
    #pragma unroll
    for (int t = 0; t < 4; ++t)
        #pragma unroll
        for (int c = 0; c < 4; ++c)
            #pragma unroll
            for (int r = 0; r < 4; ++r) {
                int row = bm + wm + t*16 + quad*4 + r;
                int col = bn + wn + c*16 + l16;
                O[(size_t)row * N + col] = acc[t][c][r];
            }
}

// ---------------- Latent k up-projection + RoPE on q,k -> bf16 (b,h,t,d) ----------------
__global__ __launch_bounds__(256) void uprope(
        const float* __restrict__ qproj, const float* __restrict__ klat,
        const float* __restrict__ Wku,
        unsigned short* __restrict__ qb, unsigned short* __restrict__ kb) {
    const int g = blockIdx.x * 4 + (threadIdx.x >> 6);
    const int d = threadIdx.x & 63;
    const int h = g & (NHEAD - 1);
    const int bt = g >> 4;
    const int t = bt & (TSEQ - 1);
    const int b = bt >> 11;
    const float* kl = klat + (size_t)bt * (NHEAD*DLAT) + h*DLAT;
    const float* wk = Wku + d*DLAT;
    float ka = 0.f;
    #pragma unroll
    for (int l = 0; l < DLAT; ++l) ka += kl[l] * wk[l];
    float qv = qproj[(size_t)bt * CDIM + h*DHEAD + d];
    float inv = powf(10000.f, -(float)(d & 31) * (1.0f/32.0f));
    float c, sn;
    sincosf((float)t * inv, &sn, &c);
    float kp = __shfl_xor(ka, 1, 64);
    float qp = __shfl_xor(qv, 1, 64);
    float kro = ka * c + ((d & 1) ? kp : -kp) * sn;
    float qro = qv * c + ((d & 1) ? qp : -qp) * sn;
    size_t o = ((size_t)(b*NHEAD + h) * TSEQ + t) * DHEAD + d;
    qb[o] = f2bf(qro * 0.125f);   // fold 1/sqrt(64)
    kb[o] = f2bf(kro);
}

// ---------------- v up-projection -> bf16 V^T (b,h,d,t) ----------------
__global__ __launch_bounds__(256) void vup(
        const float* __restrict__ vlat, const float* __restrict__ Wvu,
        unsigned short* __restrict__ vt) {
    __shared__ float vs[64][33];
    const int bh = blockIdx.y;
    const int b = bh >> 4, h = bh & 15;
    const int t0 = blockIdx.x * 64;
    const int tid = threadIdx.x;
    {
        const int r = tid >> 2, cs = (tid & 3) * 8;
        const float* src = vlat + ((size_t)(b*TSEQ + t0 + r)) * (NHEAD*DLAT) + h*DLAT + cs;
        *(float4*)&vs[r][cs]   = *(const float4*)src;
        *(float4*)&vs[r][cs+4] = *(const float4*)(src + 4);
    }
    __syncthreads();
    const int tl = tid & 63;
    const int dg = tid >> 6;
    float vrow[DLAT];
    #pragma unroll
    for (int l = 0; l < DLAT; ++l) vrow[l] = vs[tl][l];
    #pragma unroll
    for (int i = 0; i < 16; ++i) {
        const int d = dg*16 + i;
        float acc = 0.f;
        #pragma unroll
        for (int l = 0; l < DLAT; ++l) acc += vrow[l] * Wvu[d*DLAT + l];
        vt[((size_t)bh*DHEAD + d) * TSEQ + t0 + tl] = f2bf(acc);
    }
}

// ---------------- Flash attention, bf16 MFMA, bf16 output ----------------
__global__ __launch_bounds__(256) void flash_attn(
        const unsigned short* __restrict__ qb, const unsigned short* __restrict__ kb,
        const unsigned short* __restrict__ vtb, unsigned short* __restrict__ yatt) {
    const int qt = gridDim.x - 1 - blockIdx.x;   // long blocks first
    const int bh = blockIdx.y;
    const int b = bh >> 4, h = bh & 15;

    __shared__ unsigned short Ks[64][72];
    __shared__ unsigned short VTs[64][72];
    __shared__ unsigned short Ps[4][16][72];

    const int tid  = threadIdx.x;
    const int wq   = tid >> 6;
    const int lane = tid & 63;
    const int quad = lane >> 4;
    const int l16  = lane & 15;

    const unsigned short* qbase =
        qb + ((size_t)bh*TSEQ + qt*64 + wq*16 + l16) * DHEAD + quad*8;
    bf16x8 qA0 = *(const bf16x8*)qbase;
    bf16x8 qA1 = *(const bf16x8*)(qbase + 32);

    f32x4 oacc[4] = {};
    float m_run[4], l_run[4];
    #pragma unroll
    for (int r = 0; r < 4; ++r) { m_run[r] = -1e30f; l_run[r] = 0.f; }

    const int row_loc = wq*16 + quad*4;
    const unsigned short* Kbase = kb  + (size_t)bh * TSEQ * DHEAD;
    const unsigned short* Vbase = vtb + (size_t)bh * DHEAD * TSEQ;

    for (int kt = 0; kt <= qt; ++kt) {
        __syncthreads();
        #pragma unroll
        for (int i = 0; i < 2; ++i) {
            const int cid = tid + i*256;
            const int rr = cid >> 3, ss = (cid & 7) * 8;
            *(int4*)&Ks[rr][ss]  = *(const int4*)(Kbase + ((size_t)(kt*64 + rr))*DHEAD + ss);
            *(int4*)&VTs[rr][ss] = *(const int4*)(Vbase + (size_t)rr*TSEQ + kt*64 + ss);
        }
        __syncthreads();

        f32x4 sacc[4];
        #pragma unroll
        for (int c = 0; c < 4; ++c) {
            bf16x8 b0 = *(const bf16x8*)&Ks[c*16 + l16][quad*8];
            bf16x8 b1 = *(const bf16x8*)&Ks[c*16 + l16][quad*8 + 32];
            f32x4 z = {0.f, 0.f, 0.f, 0.f};
            z = __builtin_amdgcn_mfma_f32_16x16x32_bf16(qA0, b0, z, 0, 0, 0);
            z = __builtin_amdgcn_mfma_f32_16x16x32_bf16(qA1, b1, z, 0, 0, 0);
            sacc[c] = z;
        }
        if (kt == qt) {
            #pragma unroll
            for (int c = 0; c < 4; ++c)
                #pragma unroll
                for (int r = 0; r < 4; ++r)
                    if (c*16 + l16 > row_loc + r) sacc[c][r] = -1e30f;
        }

        float mx[4];
        #pragma unroll
        for (int r = 0; r < 4; ++r)
            mx[r] = fmaxf(fmaxf(sacc[0][r], sacc[1][r]), fmaxf(sacc[2][r], sacc[3][r]));
        #pragma unroll
        for (int m = 1; m < 16; m <<= 1)
            #pragma unroll
            for (int r = 0; r < 4; ++r)
                mx[r] = fmaxf(mx[r], __shfl_xor(mx[r], m, 64));
        float al[4], ls[4];
        #pragma unroll
        for (int r = 0; r < 4; ++r) {
            float mn = fmaxf(m_run[r], mx[r]);
            al[r] = __expf(m_run[r] - mn);
            m_run[r] = mn;
            ls[r] = 0.f;
        }
        #pragma unroll
        for (int c = 0; c < 4; ++c)
            #pragma unroll
            for (int r = 0; r < 4; ++r) {
                float p = __expf(sacc[c][r] - m_run[r]);
                sacc[c][r] = p;
                ls[r] += p;
            }
        #pragma unroll
        for (int m = 1; m < 16; m <<= 1)
            #pragma unroll
            for (int r = 0; r < 4; ++r)
                ls[r] += __shfl_xor(ls[r], m, 64);
        #pragma unroll
        for (int r = 0; r < 4; ++r) l_run[r] = l_run[r]*al[r] + ls[r];
        #pragma unroll
        for (int c = 0; c < 4; ++c)
            #pragma unroll
            for (int r = 0; r < 4; ++r) oacc[c][r] *= al[r];

        #pragma unroll
        for (int c = 0; c < 4; ++c)
            #pragma unroll
            for (int r = 0; r < 4; ++r)
                Ps[wq][quad*4 + r][c*16 + l16] = f2bf(sacc[c][r]);
        bf16x8 aP0 = *(const bf16x8*)&Ps[wq][l16][quad*8];
        bf16x8 aP1 = *(const bf16x8*)&Ps[wq][l16][quad*8 + 32];

        #pragma unroll
        for (int c = 0; c < 4; ++c) {
            bf16x8 bv0 = *(const bf16x8*)&VTs[c*16 + l16][quad*8];
            bf16x8 bv1 = *(const bf16x8*)&VTs[c*16 + l16][quad*8 + 32];
            oacc[c] = __builtin_amdgcn_mfma_f32_16x16x32_bf16(aP0, bv0, oacc[c], 0, 0, 0);
            oacc[c] = __builtin_amdgcn_mfma_f32_16x16x32_bf16(aP1, bv1, oacc[c], 0, 0, 0);
        }
    }

    float invl[4];
    #pragma unroll
    for (int r = 0; r < 4; ++r) invl[r] = 1.0f / l_run[r];
    unsigned short* yp = yatt + ((size_t)(b*TSEQ) + qt*64 + row_loc) * CDIM + h*DHEAD;
    #pragma unroll
    for (int r = 0; r < 4; ++r)
        #pragma unroll
        for (int c = 0; c < 4; ++c)
            yp[(size_t)r*CDIM + c*16 + l16] = f2bf(oacc[c][r] * invl[r]);
}

extern "C" void kernel_launch(void* const* d_in, const int* in_sizes, int n_in,
                              void* d_out, int out_size, void* d_ws, size_t ws_size,
                              hipStream_t stream) {
    const float* x   = (const float*)d_in[0];
    const float* Wq  = (const float*)d_in[1];
    const float* Wk  = (const float*)d_in[2];
    const float* Wv  = (const float*)d_in[3];
    const float* Wku = (const float*)d_in[4];
    const float* Wvu = (const float*)d_in[5];
    const float* Wc  = (const float*)d_in[6];

    float* out_y  = (float*)d_out;
    float* out_kl = out_y  + (size_t)MROWS * CDIM;
    float* out_vl = out_kl + (size_t)MROWS * NHEAD*DLAT;

    // workspace layout
    float* qproj = (float*)d_ws;                                   // 16 MB fp32
    unsigned short* xb   = (unsigned short*)(qproj + (size_t)MROWS*CDIM);  // 8 MB
    unsigned short* qb   = xb  + (size_t)MROWS*CDIM;               // 8 MB
    unsigned short* kb   = qb  + (size_t)MROWS*CDIM;               // 8 MB
    unsigned short* vt   = kb  + (size_t)MROWS*CDIM;               // 8 MB
    unsigned short* wall = vt  + (size_t)MROWS*CDIM;               // [Wq;Wk;Wv] 2048x1024, 4 MB
    unsigned short* wcb  = wall + (size_t)2048*CDIM;               // 2 MB
    unsigned short* yatt = (unsigned short*)qproj;  // alias: qproj dead after uprope

    // fp32 -> bf16
    cvt_bf16<<<(MROWS*CDIM)/1024, 256, 0, stream>>>(x,  xb, MROWS*CDIM);
    cvt_bf16<<<(1024*CDIM)/1024, 256, 0, stream>>>(Wq, wall,              1024*CDIM);
    cvt_bf16<<<(512*CDIM)/1024,  256, 0, stream>>>(Wk, wall + 1024*CDIM, 512*CDIM);
    cvt_bf16<<<(512*CDIM)/1024,  256, 0, stream>>>(Wv, wall + 1536*CDIM, 512*CDIM);
    cvt_bf16<<<(1024*CDIM)/1024, 256, 0, stream>>>(Wc, wcb,              1024*CDIM);

    // fused q/k/v projection (17.2 GF, one MFMA GEMM)
    gemm_proj<<<dim3(2048/128, MROWS/128), 256, 0, stream>>>(
        xb, wall, qproj, out_kl, out_vl, CDIM);

    uprope<<<(MROWS*NHEAD)/4, 256, 0, stream>>>(qproj, out_kl, Wku, qb, kb);
    vup<<<dim3(TSEQ/64, NBATCH*NHEAD), 256, 0, stream>>>(out_vl, Wvu, vt);

    flash_attn<<<dim3(TSEQ/64, NBATCH*NHEAD), 256, 0, stream>>>(qb, kb, vt, yatt);

    gemm_out<<<dim3(CDIM/128, MROWS/128), 256, 0, stream>>>(yatt, wcb, out_y, CDIM, CDIM);
}

// Round 4
// 334.219 us; speedup vs baseline: 6.9328x; 1.1065x over previous
//
#include <hip/hip_runtime.h>
#include <math.h>

#define NHEAD  16
#define DHEAD  64
#define DLAT   32
#define TSEQ   2048
#define NBATCH 2
#define CDIM   1024
#define MROWS  (NBATCH*TSEQ)   // 4096

typedef __attribute__((ext_vector_type(8))) short bf16x8;
typedef __attribute__((ext_vector_type(4))) float f32x4;

#define AS1 __attribute__((address_space(1)))
#define AS3 __attribute__((address_space(3)))

__device__ __forceinline__ unsigned short f2bf(float f) {
    union { float f; unsigned u; } v; v.f = f;
    unsigned r = v.u + 0x7fff + ((v.u >> 16) & 1);   // RNE
    return (unsigned short)(r >> 16);
}

__device__ __forceinline__ void gld_lds16(const unsigned short* g, unsigned short* l) {
    __builtin_amdgcn_global_load_lds((const AS1 void*)g, (AS3 void*)l, 16, 0, 0);
}

// ---------------- fp32 -> bf16 conversions ----------------
__global__ __launch_bounds__(256) void cvt_bf16(const float* __restrict__ src,
        unsigned short* __restrict__ dst, int n) {
    int i = (blockIdx.x * 256 + threadIdx.x) * 4;
    if (i < n) {
        float4 v = *(const float4*)(src + i);
        ushort4 o = { f2bf(v.x), f2bf(v.y), f2bf(v.z), f2bf(v.w) };
        *(ushort4*)(dst + i) = o;
    }
}

// All four weights in one launch; dst segments are contiguous ([Wq;Wk;Wv;Wc]).
__global__ __launch_bounds__(256) void cvt_w4(
        const float* __restrict__ wq, const float* __restrict__ wk,
        const float* __restrict__ wv, const float* __restrict__ wc,
        unsigned short* __restrict__ dst) {
    int i = (blockIdx.x * 256 + threadIdx.x) * 4;
    const float* src;
    int off;
    if      (i < 1024*1024)      { src = wq; off = 0; }
    else if (i < 1536*1024)      { src = wk; off = 1024*1024; }
    else if (i < 2048*1024)      { src = wv; off = 1536*1024; }
    else                         { src = wc; off = 2048*1024; }
    float4 v = *(const float4*)(src + (i - off));
    ushort4 o = { f2bf(v.x), f2bf(v.y), f2bf(v.z), f2bf(v.w) };
    *(ushort4*)(dst + i) = o;
}

// ---------------- MFMA GEMM core: 128x128 tile, BK=32, 4 waves ----------------
__device__ __forceinline__ void gemm_core(
        const unsigned short* __restrict__ A, const unsigned short* __restrict__ W,
        int K, int bm, int bn, unsigned short* As, unsigned short* Bs,
        f32x4 (&acc)[4][4]) {
    const int tid = threadIdx.x;
    const int w = tid >> 6, lane = tid & 63;
    const int quad = lane >> 4, l16 = lane & 15;
    const int wm = (w >> 1) * 64, wn = (w & 1) * 64;

    const int lr = lane >> 2;
    const int le = (lane & 3) * 8;
    const unsigned short* Ag0 = A + (size_t)(bm + w*32 + lr) * K + le;
    const unsigned short* Wg0 = W + (size_t)(bn + w*32 + lr) * K + le;
    unsigned short* AsD0 = &As[(w*32 +  0) * 32];
    unsigned short* AsD1 = &As[(w*32 + 16) * 32];
    unsigned short* BsD0 = &Bs[(w*32 +  0) * 32];
    unsigned short* BsD1 = &Bs[(w*32 + 16) * 32];

    for (int k0 = 0; k0 < K; k0 += 32) {
        gld_lds16(Ag0 + k0,                AsD0);
        gld_lds16(Ag0 + k0 + (size_t)16*K, AsD1);
        gld_lds16(Wg0 + k0,                BsD0);
        gld_lds16(Wg0 + k0 + (size_t)16*K, BsD1);
        __syncthreads();
        bf16x8 af[4], bf[4];
        #pragma unroll
        for (int t = 0; t < 4; ++t)
            af[t] = *(const bf16x8*)&As[(wm + t*16 + l16)*32 + quad*8];
        #pragma unroll
        for (int c = 0; c < 4; ++c)
            bf[c] = *(const bf16x8*)&Bs[(wn + c*16 + l16)*32 + quad*8];
        #pragma unroll
        for (int t = 0; t < 4; ++t)
            #pragma unroll
            for (int c = 0; c < 4; ++c)
                acc[t][c] = __builtin_amdgcn_mfma_f32_16x16x32_bf16(af[t], bf[c], acc[t][c], 0, 0, 0);
        __syncthreads();
    }
}

__global__ __launch_bounds__(256) void gemm_proj(
        const unsigned short* __restrict__ A, const unsigned short* __restrict__ W,
        float* __restrict__ qproj, float* __restrict__ okl, float* __restrict__ ovl,
        int K) {
    __shared__ unsigned short As[128*32];
    __shared__ unsigned short Bs[128*32];
    const int bm = blockIdx.y * 128, bn = blockIdx.x * 128;
    f32x4 acc[4][4] = {};
    gemm_core(A, W, K, bm, bn, As, Bs, acc);

    const int tid = threadIdx.x;
    const int w = tid >> 6, lane = tid & 63;
    const int quad = lane >> 4, l16 = lane & 15;
    const int wm = (w >> 1) * 64, wn = (w & 1) * 64;

    float* base; int ldo;
    if (bn < 1024)      { base = qproj + bn;        ldo = 1024; }
    else if (bn < 1536) { base = okl + (bn - 1024); ldo = 512;  }
    else                { base = ovl + (bn - 1536); ldo = 512;  }

    #pragma unroll
    for (int t = 0; t < 4; ++t)
        #pragma unroll
        for (int c = 0; c < 4; ++c)
            #pragma unroll
            for (int r = 0; r < 4; ++r) {
                int row = bm + wm + t*16 + quad*4 + r;
                int col = wn + c*16 + l16;
                base[(size_t)row * ldo + col] = acc[t][c][r];
            }
}

__global__ __launch_bounds__(256) void gemm_out(
        const unsigned short* __restrict__ A, const unsigned short* __restrict__ W,
        float* __restrict__ O, int N, int K) {
    __shared__ unsigned short As[128*32];
    __shared__ unsigned short Bs[128*32];
    const int bm = blockIdx.y * 128, bn = blockIdx.x * 128;
    f32x4 acc[4][4] = {};
    gemm_core(A, W, K, bm, bn, As, Bs, acc);

    const int tid = threadIdx.x;
    const int w = tid >> 6, lane = tid & 63;
    const int quad = lane >> 4, l16 = lane & 15;
    const int wm = (w >> 1) * 64, wn = (w & 1) * 64;
    #pragma unroll
    for (int t = 0; t < 4; ++t)
        #pragma unroll
        for (int c = 0; c < 4; ++c)
            #pragma unroll
            for (int r = 0; r < 4; ++r) {
                int row = bm + wm + t*16 + quad*4 + r;
                int col = bn + wn + c*16 + l16;
                O[(size_t)row * N + col] = acc[t][c][r];
            }
}

// ---------------- Latent k up-projection + RoPE on q,k -> bf16 (b,h,t,d) ----------------
__global__ __launch_bounds__(256) void uprope(
        const float* __restrict__ qproj, const float* __restrict__ klat,
        const float* __restrict__ Wku,
        unsigned short* __restrict__ qb, unsigned short* __restrict__ kb) {
    const int g = blockIdx.x * 4 + (threadIdx.x >> 6);
    const int d = threadIdx.x & 63;
    const int h = g & (NHEAD - 1);
    const int bt = g >> 4;
    const int t = bt & (TSEQ - 1);
    const int b = bt >> 11;
    const float* kl = klat + (size_t)bt * (NHEAD*DLAT) + h*DLAT;
    const float* wk = Wku + d*DLAT;
    float ka = 0.f;
    #pragma unroll
    for (int l = 0; l < DLAT; ++l) ka += kl[l] * wk[l];
    float qv = qproj[(size_t)bt * CDIM + h*DHEAD + d];
    float inv = __expf(-(float)(d & 31) * (0.2878231366f));  // ln(10000)/32
    float c, sn;
    __sincosf((float)t * inv, &sn, &c);
    float kp = __shfl_xor(ka, 1, 64);
    float qp = __shfl_xor(qv, 1, 64);
    float kro = ka * c + ((d & 1) ? kp : -kp) * sn;
    float qro = qv * c + ((d & 1) ? qp : -qp) * sn;
    size_t o = ((size_t)(b*NHEAD + h) * TSEQ + t) * DHEAD + d;
    qb[o] = f2bf(qro * 0.125f);
    kb[o] = f2bf(kro);
}

// ---------------- v up-projection -> bf16 V^T (b,h,d,t) ----------------
__global__ __launch_bounds__(256) void vup(
        const float* __restrict__ vlat, const float* __restrict__ Wvu,
        unsigned short* __restrict__ vt) {
    __shared__ float vs[64][33];
    const int bh = blockIdx.y;
    const int b = bh >> 4, h = bh & 15;
    const int t0 = blockIdx.x * 64;
    const int tid = threadIdx.x;
    {
        const int r = tid >> 2, cs = (tid & 3) * 8;
        const float* src = vlat + ((size_t)(b*TSEQ + t0 + r)) * (NHEAD*DLAT) + h*DLAT + cs;
        *(float4*)&vs[r][cs]   = *(const float4*)src;
        *(float4*)&vs[r][cs+4] = *(const float4*)(src + 4);
    }
    __syncthreads();
    const int tl = tid & 63;
    const int dg = tid >> 6;
    float vrow[DLAT];
    #pragma unroll
    for (int l = 0; l < DLAT; ++l) vrow[l] = vs[tl][l];
    #pragma unroll
    for (int i = 0; i < 16; ++i) {
        const int d = dg*16 + i;
        float acc = 0.f;
        #pragma unroll
        for (int l = 0; l < DLAT; ++l) acc += vrow[l] * Wvu[d*DLAT + l];
        vt[((size_t)bh*DHEAD + d) * TSEQ + t0 + tl] = f2bf(acc);
    }
}

// ---------------- Flash attention: S^T orientation, reg-prefetch, LDS dbuf ----------------
// S^T = K·Q^T  (C-layout: row=kcol=quad*4+r+16c, col=qrow=l16) -> per-lane scalar m/l,
// 2-step shfl reductions. P^T B-frags built with ds_bpermute (no LDS round-trip).
// O^T = V^T·P^T accumulated in C-layout (row=d, col=qrow); transposed via LDS at epilogue.
__global__ __launch_bounds__(256) void flash_attn(
        const unsigned short* __restrict__ qb, const unsigned short* __restrict__ kb,
        const unsigned short* __restrict__ vtb, unsigned short* __restrict__ yatt) {
    const int bh = blockIdx.x;                    // longest blocks dispatch first (y=0 -> qt max)
    const int qt = (TSEQ/64 - 1) - blockIdx.y;
    const int b = bh >> 4, h = bh & 15;

    __shared__ unsigned short Ks[2][64][72];      // K tile (t,d)
    __shared__ unsigned short VTs[2][64][72];     // V^T tile (d,t)

    const int tid  = threadIdx.x;
    const int wq   = tid >> 6;
    const int lane = tid & 63;
    const int quad = lane >> 4;
    const int l16  = lane & 15;

    // Q fragment (B-operand of S^T): lane holds Q[qrow=wq*16+l16][d=quad*8+j]
    const unsigned short* qbase =
        qb + ((size_t)bh*TSEQ + qt*64 + wq*16 + l16) * DHEAD + quad*8;
    bf16x8 qB0 = *(const bf16x8*)qbase;
    bf16x8 qB1 = *(const bf16x8*)(qbase + 32);

    f32x4 oacc[4] = {};        // O^T: rows d = c*16+quad*4+r, col qrow=l16
    float m_run = -1e30f, l_run = 0.f;

    const unsigned short* Kbase = kb  + (size_t)bh * TSEQ * DHEAD;
    const unsigned short* Vbase = vtb + (size_t)bh * DHEAD * TSEQ;

    const int srr = tid >> 3;                // staging row (with +256 offset for i=1)
    const int sss = (tid & 7) * 8;
    const int srr1 = (tid + 256) >> 3;

    int4 kreg[2], vreg[2];
    // preload kt=0
    kreg[0] = *(const int4*)(Kbase + (size_t)srr  * DHEAD + sss);
    kreg[1] = *(const int4*)(Kbase + (size_t)srr1 * DHEAD + sss);
    vreg[0] = *(const int4*)(Vbase + (size_t)srr  * TSEQ + sss);
    vreg[1] = *(const int4*)(Vbase + (size_t)srr1 * TSEQ + sss);
    *(int4*)&Ks[0][srr][sss]   = kreg[0];
    *(int4*)&Ks[0][srr1][sss]  = kreg[1];
    *(int4*)&VTs[0][srr][sss]  = vreg[0];
    *(int4*)&VTs[0][srr1][sss] = vreg[1];
    __syncthreads();

    const int idx01 = (((lane >> 4) & 1) * 32 + l16) * 4;
    const int idx23 = idx01 + 64;
    const bool hi = (lane & 32) != 0;

    for (int kt = 0; kt <= qt; ++kt) {
        const int buf = kt & 1;
        if (kt < qt) {   // prefetch next tile into regs (overlaps with compute below)
            kreg[0] = *(const int4*)(Kbase + (size_t)((kt+1)*64 + srr)  * DHEAD + sss);
            kreg[1] = *(const int4*)(Kbase + (size_t)((kt+1)*64 + srr1) * DHEAD + sss);
            vreg[0] = *(const int4*)(Vbase + (size_t)srr  * TSEQ + (kt+1)*64 + sss);
            vreg[1] = *(const int4*)(Vbase + (size_t)srr1 * TSEQ + (kt+1)*64 + sss);
        }

        // S^T = K Q^T  (A = K rows, B = Q)
        f32x4 sacc[4];
        #pragma unroll
        for (int c = 0; c < 4; ++c) {
            bf16x8 ak0 = *(const bf16x8*)&Ks[buf][c*16 + l16][quad*8];
            bf16x8 ak1 = *(const bf16x8*)&Ks[buf][c*16 + l16][quad*8 + 32];
            f32x4 z = {0.f, 0.f, 0.f, 0.f};
            z = __builtin_amdgcn_mfma_f32_16x16x32_bf16(ak0, qB0, z, 0, 0, 0);
            z = __builtin_amdgcn_mfma_f32_16x16x32_bf16(ak1, qB1, z, 0, 0, 0);
            sacc[c] = z;
        }
        if (kt == qt) {   // causal mask: kcol_local > qrow_local
            #pragma unroll
            for (int c = 0; c < 4; ++c)
                #pragma unroll
                for (int r = 0; r < 4; ++r)
                    if (c*16 + quad*4 + r > wq*16 + l16) sacc[c][r] = -1e30f;
        }

        // online softmax: per-lane scalar row stats, 2-step cross-quad reduce
        float mx = -1e30f;
        #pragma unroll
        for (int c = 0; c < 4; ++c)
            #pragma unroll
            for (int r = 0; r < 4; ++r) mx = fmaxf(mx, sacc[c][r]);
        mx = fmaxf(mx, __shfl_xor(mx, 16, 64));
        mx = fmaxf(mx, __shfl_xor(mx, 32, 64));
        float mn = fmaxf(m_run, mx);
        float alpha = __expf(m_run - mn);
        m_run = mn;
        float ls = 0.f;
        #pragma unroll
        for (int c = 0; c < 4; ++c)
            #pragma unroll
            for (int r = 0; r < 4; ++r) {
                float p = __expf(sacc[c][r] - mn);
                sacc[c][r] = p;
                ls += p;
            }
        ls += __shfl_xor(ls, 16, 64);
        ls += __shfl_xor(ls, 32, 64);
        l_run = l_run * alpha + ls;
        #pragma unroll
        for (int c = 0; c < 4; ++c)
            #pragma unroll
            for (int r = 0; r < 4; ++r) oacc[c][r] *= alpha;

        // P^T B-frags via register lane-permute (no LDS, no conflicts)
        unsigned pk[4][2];
        #pragma unroll
        for (int c = 0; c < 4; ++c) {
            pk[c][0] = (unsigned)f2bf(sacc[c][0]) | ((unsigned)f2bf(sacc[c][1]) << 16);
            pk[c][1] = (unsigned)f2bf(sacc[c][2]) | ((unsigned)f2bf(sacc[c][3]) << 16);
        }
        union { bf16x8 v; int d[4]; } bP0, bP1;
        #pragma unroll
        for (int jj = 0; jj < 4; ++jj) {
            int idx = (jj < 2) ? idx01 : idx23;
            int u = jj & 1;
            int a0 = __builtin_amdgcn_ds_bpermute(idx, (int)pk[0][u]);
            int b0 = __builtin_amdgcn_ds_bpermute(idx, (int)pk[1][u]);
            bP0.d[jj] = hi ? b0 : a0;
            int a1 = __builtin_amdgcn_ds_bpermute(idx, (int)pk[2][u]);
            int b1 = __builtin_amdgcn_ds_bpermute(idx, (int)pk[3][u]);
            bP1.d[jj] = hi ? b1 : a1;
        }

        // O^T += V^T P^T
        #pragma unroll
        for (int c = 0; c < 4; ++c) {
            bf16x8 av0 = *(const bf16x8*)&VTs[buf][c*16 + l16][quad*8];
            bf16x8 av1 = *(const bf16x8*)&VTs[buf][c*16 + l16][quad*8 + 32];
            oacc[c] = __builtin_amdgcn_mfma_f32_16x16x32_bf16(av0, bP0.v, oacc[c], 0, 0, 0);
            oacc[c] = __builtin_amdgcn_mfma_f32_16x16x32_bf16(av1, bP1.v, oacc[c], 0, 0, 0);
        }

        if (kt < qt) {   // stage prefetched regs into the other buffer
            *(int4*)&Ks[buf^1][srr][sss]   = kreg[0];
            *(int4*)&Ks[buf^1][srr1][sss]  = kreg[1];
            *(int4*)&VTs[buf^1][srr][sss]  = vreg[0];
            *(int4*)&VTs[buf^1][srr1][sss] = vreg[1];
        }
        __syncthreads();
    }

    // epilogue: O^T -> O via per-wave LDS region, then coalesced 16B stores
    float invl = 1.0f / l_run;
    unsigned short* Wt = &Ks[0][0][0] + wq * (16*72);
    #pragma unroll
    for (int c = 0; c < 4; ++c)
        #pragma unroll
        for (int r = 0; r < 4; ++r)
            Wt[(size_t)l16*72 + c*16 + quad*4 + r] = f2bf(oacc[c][r] * invl);
    __asm__ __volatile__("" ::: "memory");   // keep DS order (same-wave, in-order pipe)
    #pragma unroll
    for (int p = 0; p < 2; ++p) {
        int row = p*8 + (lane >> 3);
        int d0 = (lane & 7) * 8;
        int4 val = *(const int4*)&Wt[row*72 + d0];
        int tg = qt*64 + wq*16 + row;
        *(int4*)&yatt[((size_t)(b*TSEQ + tg))*CDIM + h*DHEAD + d0] = val;
    }
}

extern "C" void kernel_launch(void* const* d_in, const int* in_sizes, int n_in,
                              void* d_out, int out_size, void* d_ws, size_t ws_size,
                              hipStream_t stream) {
    const float* x   = (const float*)d_in[0];
    const float* Wq  = (const float*)d_in[1];
    const float* Wk  = (const float*)d_in[2];
    const float* Wv  = (const float*)d_in[3];
    const float* Wku = (const float*)d_in[4];
    const float* Wvu = (const float*)d_in[5];
    const float* Wc  = (const float*)d_in[6];

    float* out_y  = (float*)d_out;
    float* out_kl = out_y  + (size_t)MROWS * CDIM;
    float* out_vl = out_kl + (size_t)MROWS * NHEAD*DLAT;

    float* qproj = (float*)d_ws;                                           // 16 MB fp32
    unsigned short* xb   = (unsigned short*)(qproj + (size_t)MROWS*CDIM);  // 8 MB
    unsigned short* qb   = xb  + (size_t)MROWS*CDIM;                       // 8 MB
    unsigned short* kb   = qb  + (size_t)MROWS*CDIM;                       // 8 MB
    unsigned short* vt   = kb  + (size_t)MROWS*CDIM;                       // 8 MB
    unsigned short* wall = vt  + (size_t)MROWS*CDIM;                       // [Wq;Wk;Wv;Wc] 6 MB
    unsigned short* wcb  = wall + (size_t)2048*CDIM;
    unsigned short* yatt = (unsigned short*)qproj;   // alias: qproj dead after uprope

    cvt_bf16<<<(MROWS*CDIM)/1024, 256, 0, stream>>>(x, xb, MROWS*CDIM);
    cvt_w4<<<(3072*CDIM)/1024, 256, 0, stream>>>(Wq, Wk, Wv, Wc, wall);

    gemm_proj<<<dim3(2048/128, MROWS/128), 256, 0, stream>>>(
        xb, wall, qproj, out_kl, out_vl, CDIM);

    uprope<<<(MROWS*NHEAD)/4, 256, 0, stream>>>(qproj, out_kl, Wku, qb, kb);
    vup<<<dim3(TSEQ/64, NBATCH*NHEAD), 256, 0, stream>>>(out_vl, Wvu, vt);

    flash_attn<<<dim3(NBATCH*NHEAD, TSEQ/64), 256, 0, stream>>>(qb, kb, vt, yatt);

    gemm_out<<<dim3(CDIM/128, MROWS/128), 256, 0, stream>>>(yatt, wcb, out_y, CDIM, CDIM);
}

// Round 5
// 279.613 us; speedup vs baseline: 8.2867x; 1.1953x over previous
//
#include <hip/hip_runtime.h>
#include <math.h>

#define NHEAD  16
#define DHEAD  64
#define DLAT   32
#define TSEQ   2048
#define NBATCH 2
#define CDIM   1024
#define MROWS  (NBATCH*TSEQ)   // 4096

typedef __attribute__((ext_vector_type(8))) short bf16x8;
typedef __attribute__((ext_vector_type(4))) float f32x4;

#define AS1 __attribute__((address_space(1)))
#define AS3 __attribute__((address_space(3)))

__device__ __forceinline__ unsigned short f2bf(float f) {
    union { float f; unsigned u; } v; v.f = f;
    unsigned r = v.u + 0x7fff + ((v.u >> 16) & 1);   // RNE
    return (unsigned short)(r >> 16);
}

// pack bf16(lo)|bf16(hi)<<16 by truncation — one v_perm_b32
__device__ __forceinline__ unsigned pack_trunc(float hi, float lo) {
    return __builtin_amdgcn_perm(__float_as_uint(hi), __float_as_uint(lo), 0x07060302u);
}

__device__ __forceinline__ void gld_lds16(const unsigned short* g, unsigned short* l) {
    __builtin_amdgcn_global_load_lds((const AS1 void*)g, (AS3 void*)l, 16, 0, 0);
}

// ---------------- fp32 -> bf16: x and all four weights in ONE launch ----------------
// dst layout: xb (4096x1024) separate; wall = [Wq;Wk;Wv;Wc] contiguous.
__global__ __launch_bounds__(256) void cvt_all(
        const float* __restrict__ x,  const float* __restrict__ wq,
        const float* __restrict__ wk, const float* __restrict__ wv,
        const float* __restrict__ wc,
        unsigned short* __restrict__ xb, unsigned short* __restrict__ wall) {
    int i = (blockIdx.x * 256 + threadIdx.x) * 4;
    const float* src; unsigned short* dst; int off;
    if      (i < 4194304) { src = x;  dst = xb;             off = 0;       }
    else if (i < 5242880) { src = wq; dst = wall;           off = 4194304; }
    else if (i < 5767168) { src = wk; dst = wall + 1048576; off = 5242880; }
    else if (i < 6291456) { src = wv; dst = wall + 1572864; off = 5767168; }
    else                  { src = wc; dst = wall + 2097152; off = 6291456; }
    float4 v = *(const float4*)(src + (i - off));
    ushort4 o = { f2bf(v.x), f2bf(v.y), f2bf(v.z), f2bf(v.w) };
    *(ushort4*)(dst + (i - off)) = o;
}

// ---------------- MFMA GEMM core: 128x128 tile, BK=32, 4 waves ----------------
__device__ __forceinline__ void gemm_core(
        const unsigned short* __restrict__ A, const unsigned short* __restrict__ W,
        int K, int bm, int bn, unsigned short* As, unsigned short* Bs,
        f32x4 (&acc)[4][4]) {
    const int tid = threadIdx.x;
    const int w = tid >> 6, lane = tid & 63;
    const int quad = lane >> 4, l16 = lane & 15;
    const int wm = (w >> 1) * 64, wn = (w & 1) * 64;

    const int lr = lane >> 2;
    const int le = (lane & 3) * 8;
    const unsigned short* Ag0 = A + (size_t)(bm + w*32 + lr) * K + le;
    const unsigned short* Wg0 = W + (size_t)(bn + w*32 + lr) * K + le;
    unsigned short* AsD0 = &As[(w*32 +  0) * 32];
    unsigned short* AsD1 = &As[(w*32 + 16) * 32];
    unsigned short* BsD0 = &Bs[(w*32 +  0) * 32];
    unsigned short* BsD1 = &Bs[(w*32 + 16) * 32];

    for (int k0 = 0; k0 < K; k0 += 32) {
        gld_lds16(Ag0 + k0,                AsD0);
        gld_lds16(Ag0 + k0 + (size_t)16*K, AsD1);
        gld_lds16(Wg0 + k0,                BsD0);
        gld_lds16(Wg0 + k0 + (size_t)16*K, BsD1);
        __syncthreads();
        bf16x8 af[4], bf[4];
        #pragma unroll
        for (int t = 0; t < 4; ++t)
            af[t] = *(const bf16x8*)&As[(wm + t*16 + l16)*32 + quad*8];
        #pragma unroll
        for (int c = 0; c < 4; ++c)
            bf[c] = *(const bf16x8*)&Bs[(wn + c*16 + l16)*32 + quad*8];
        #pragma unroll
        for (int t = 0; t < 4; ++t)
            #pragma unroll
            for (int c = 0; c < 4; ++c)
                acc[t][c] = __builtin_amdgcn_mfma_f32_16x16x32_bf16(af[t], bf[c], acc[t][c], 0, 0, 0);
        __syncthreads();
    }
}

__global__ __launch_bounds__(256) void gemm_proj(
        const unsigned short* __restrict__ A, const unsigned short* __restrict__ W,
        float* __restrict__ qproj, float* __restrict__ okl, float* __restrict__ ovl,
        int K) {
    __shared__ unsigned short As[128*32];
    __shared__ unsigned short Bs[128*32];
    const int bm = blockIdx.y * 128, bn = blockIdx.x * 128;
    f32x4 acc[4][4] = {};
    gemm_core(A, W, K, bm, bn, As, Bs, acc);

    const int tid = threadIdx.x;
    const int w = tid >> 6, lane = tid & 63;
    const int quad = lane >> 4, l16 = lane & 15;
    const int wm = (w >> 1) * 64, wn = (w & 1) * 64;

    float* base; int ldo;
    if (bn < 1024)      { base = qproj + bn;        ldo = 1024; }
    else if (bn < 1536) { base = okl + (bn - 1024); ldo = 512;  }
    else                { base = ovl + (bn - 1536); ldo = 512;  }

    #pragma unroll
    for (int t = 0; t < 4; ++t)
        #pragma unroll
        for (int c = 0; c < 4; ++c)
            #pragma unroll
            for (int r = 0; r < 4; ++r) {
                int row = bm + wm + t*16 + quad*4 + r;
                int col = wn + c*16 + l16;
                base[(size_t)row * ldo + col] = acc[t][c][r];
            }
}

__global__ __launch_bounds__(256) void gemm_out(
        const unsigned short* __restrict__ A, const unsigned short* __restrict__ W,
        float* __restrict__ O, int N, int K) {
    __shared__ unsigned short As[128*32];
    __shared__ unsigned short Bs[128*32];
    const int bm = blockIdx.y * 128, bn = blockIdx.x * 128;
    f32x4 acc[4][4] = {};
    gemm_core(A, W, K, bm, bn, As, Bs, acc);

    const int tid = threadIdx.x;
    const int w = tid >> 6, lane = tid & 63;
    const int quad = lane >> 4, l16 = lane & 15;
    const int wm = (w >> 1) * 64, wn = (w & 1) * 64;
    #pragma unroll
    for (int t = 0; t < 4; ++t)
        #pragma unroll
        for (int c = 0; c < 4; ++c)
            #pragma unroll
            for (int r = 0; r < 4; ++r) {
                int row = bm + wm + t*16 + quad*4 + r;
                int col = bn + wn + c*16 + l16;
                O[(size_t)row * N + col] = acc[t][c][r];
            }
}

// ---------------- fused latent up-proj (k,v) + q load + RoPE -> qb,kb,(b,h,t,d); vt (b,h,d,t) ----------------
// Block = (t-tile of 64, bh). Wave-uniform d-group (tid>>6) keeps Wku/Wvu loads scalar.
__global__ __launch_bounds__(256) void latup(
        const float* __restrict__ qproj, const float* __restrict__ klat,
        const float* __restrict__ vlat,  const float* __restrict__ Wku,
        const float* __restrict__ Wvu,
        unsigned short* __restrict__ qb, unsigned short* __restrict__ kb,
        unsigned short* __restrict__ vt) {
    __shared__ float kls[64][36];
    __shared__ float vls[64][36];
    __shared__ unsigned short vts[64][72];
    const int bh = blockIdx.y, b = bh >> 4, h = bh & 15;
    const int t0 = blockIdx.x * 64;
    const int tid = threadIdx.x;
    {   // stage klat / vlat tiles (64 t x 32 l fp32)
        const int r = tid >> 2, cs = (tid & 3) * 8;
        const float* ksrc = klat + ((size_t)(b*TSEQ + t0 + r))*(NHEAD*DLAT) + h*DLAT + cs;
        const float* vsrc = vlat + ((size_t)(b*TSEQ + t0 + r))*(NHEAD*DLAT) + h*DLAT + cs;
        *(float4*)&kls[r][cs]   = *(const float4*)ksrc;
        *(float4*)&kls[r][cs+4] = *(const float4*)(ksrc + 4);
        *(float4*)&vls[r][cs]   = *(const float4*)vsrc;
        *(float4*)&vls[r][cs+4] = *(const float4*)(vsrc + 4);
    }
    __syncthreads();
    const int tl = tid & 63;       // t within tile
    const int dg = tid >> 6;       // wave-uniform d-group (16 d's)
    const int t = t0 + tl;

    float ca[16], sa[16];
    #pragma unroll
    for (int i = 0; i < 16; ++i) {
        int d = dg*16 + i;
        float inv = __expf(-(float)(d & 31) * 0.28782313662425572f);  // ln(10000)/32
        __sincosf((float)t * inv, &sa[i], &ca[i]);
    }
    float kl_r[DLAT], vl_r[DLAT];
    #pragma unroll
    for (int l = 0; l < DLAT; ++l) { kl_r[l] = kls[tl][l]; vl_r[l] = vls[tl][l]; }

    float kv[16], vv[16], qv[16];
    #pragma unroll
    for (int i = 0; i < 16; ++i) {
        int d = dg*16 + i;
        float a0 = 0.f, a1 = 0.f;
        #pragma unroll
        for (int l = 0; l < DLAT; ++l) {
            a0 += kl_r[l] * Wku[d*DLAT + l];
            a1 += vl_r[l] * Wvu[d*DLAT + l];
        }
        kv[i] = a0; vv[i] = a1;
    }
    {
        const float* qsrc = qproj + ((size_t)(b*TSEQ + t))*CDIM + h*DHEAD + dg*16;
        #pragma unroll
        for (int i = 0; i < 4; ++i) {
            float4 v4 = *(const float4*)(qsrc + i*4);
            qv[i*4+0]=v4.x; qv[i*4+1]=v4.y; qv[i*4+2]=v4.z; qv[i*4+3]=v4.w;
        }
    }
    // RoPE pairs (within-thread; pairs never cross the 16-wide group) + RNE pack
    unsigned kw[8], qw[8];
    #pragma unroll
    for (int i = 0; i < 8; ++i) {
        int e = 2*i, o = e + 1;
        float ke = kv[e]*ca[e] - kv[o]*sa[e];
        float ko = kv[o]*ca[o] + kv[e]*sa[o];
        float qe = (qv[e]*ca[e] - qv[o]*sa[e]) * 0.125f;
        float qo = (qv[o]*ca[o] + qv[e]*sa[o]) * 0.125f;
        kw[i] = (unsigned)f2bf(ke) | ((unsigned)f2bf(ko) << 16);
        qw[i] = (unsigned)f2bf(qe) | ((unsigned)f2bf(qo) << 16);
    }
    size_t orow = ((size_t)bh*TSEQ + t)*DHEAD + dg*16;
    *(int4*)&kb[orow]     = make_int4(kw[0], kw[1], kw[2], kw[3]);
    *(int4*)&kb[orow + 8] = make_int4(kw[4], kw[5], kw[6], kw[7]);
    *(int4*)&qb[orow]     = make_int4(qw[0], qw[1], qw[2], qw[3]);
    *(int4*)&qb[orow + 8] = make_int4(qw[4], qw[5], qw[6], qw[7]);

    // v: transpose through LDS, then coalesced row writes of V^T
    #pragma unroll
    for (int i = 0; i < 16; ++i) vts[dg*16 + i][tl] = f2bf(vv[i]);
    __syncthreads();
    const int r2 = tid >> 2, c2 = (tid & 3) * 16;
    int4 w0 = *(const int4*)&vts[r2][c2];
    int4 w1 = *(const int4*)&vts[r2][c2 + 8];
    unsigned short* vdst = vt + ((size_t)bh*DHEAD + r2)*TSEQ + t0 + c2;
    *(int4*)&vdst[0] = w0;
    *(int4*)&vdst[8] = w1;
}

// ---------------- Flash attention: paired Q-tiles (uniform blocks), K-tile=128 ----------------
// Block (bh, y) processes Q-tiles qt=y and qt=31-y sequentially: (y+1)+(32-y)=33 64-tiles
// = 17 128-iters for every block -> zero tail, 512 blocks = exactly 2/CU.
__global__ __launch_bounds__(256) void flash_attn(
        const unsigned short* __restrict__ qb, const unsigned short* __restrict__ kb,
        const unsigned short* __restrict__ vtb, unsigned short* __restrict__ yatt) {
    const int bh = blockIdx.x;
    const int b = bh >> 4, h = bh & 15;

    __shared__ unsigned short Ks[2][128][72];    // K tile (t,d), 144B rows (16B-aligned)
    __shared__ unsigned short VTs[2][64][136];   // V^T tile (d,t), 272B rows

    const int tid  = threadIdx.x;
    const int wq   = tid >> 6;
    const int lane = tid & 63;
    const int quad = lane >> 4;
    const int l16  = lane & 15;

    const unsigned short* Kbase = kb  + (size_t)bh * TSEQ * DHEAD;
    const unsigned short* Vbase = vtb + (size_t)bh * DHEAD * TSEQ;

    const int krr = tid >> 1, kso = (tid & 1) * 32;   // K staging: row, elem offset (4x int4)
    const int vrr = tid >> 2, vso = (tid & 3) * 32;   // V staging

    const int idx01 = (((lane >> 4) & 1) * 32 + l16) * 4;
    const int idx23 = idx01 + 64;
    const bool hi = (lane & 32) != 0;

    for (int half = 0; half < 2; ++half) {
        const int qt = half ? (31 - (int)blockIdx.y) : (int)blockIdx.y;
        const int n128 = (qt + 2) >> 1;

        const unsigned short* qbase =
            qb + ((size_t)bh*TSEQ + qt*64 + wq*16 + l16) * DHEAD + quad*8;
        bf16x8 qB0 = *(const bf16x8*)qbase;
        bf16x8 qB1 = *(const bf16x8*)(qbase + 32);

        f32x4 oacc[4] = {};
        float m_run = -1e30f, l_run = 0.f;

        __syncthreads();   // previous half's epilogue LDS reads done
        int4 kreg[4], vreg[4];
        #pragma unroll
        for (int a = 0; a < 4; ++a) {
            kreg[a] = *(const int4*)(Kbase + (size_t)krr * DHEAD + kso + a*8);
            vreg[a] = *(const int4*)(Vbase + (size_t)vrr * TSEQ + vso + a*8);
        }
        #pragma unroll
        for (int a = 0; a < 4; ++a) {
            *(int4*)&Ks[0][krr][kso + a*8]  = kreg[a];
            *(int4*)&VTs[0][vrr][vso + a*8] = vreg[a];
        }
        __syncthreads();

        for (int j = 0; j < n128; ++j) {
            const int buf = j & 1;
            if (j + 1 < n128) {   // register prefetch of next 128-wide K/V tile
                const int kc = (j + 1) * 128;
                #pragma unroll
                for (int a = 0; a < 4; ++a) {
                    kreg[a] = *(const int4*)(Kbase + (size_t)(kc + krr) * DHEAD + kso + a*8);
                    vreg[a] = *(const int4*)(Vbase + (size_t)vrr * TSEQ + kc + vso + a*8);
                }
            }

            // S^T = K Q^T  (8 chunks of 16 K-rows)
            f32x4 sacc[8];
            #pragma unroll
            for (int c = 0; c < 8; ++c) {
                bf16x8 ak0 = *(const bf16x8*)&Ks[buf][c*16 + l16][quad*8];
                bf16x8 ak1 = *(const bf16x8*)&Ks[buf][c*16 + l16][quad*8 + 32];
                f32x4 z = {0.f, 0.f, 0.f, 0.f};
                z = __builtin_amdgcn_mfma_f32_16x16x32_bf16(ak0, qB0, z, 0, 0, 0);
                z = __builtin_amdgcn_mfma_f32_16x16x32_bf16(ak1, qB1, z, 0, 0, 0);
                sacc[c] = z;
            }
            if (j == n128 - 1) {   // causal mask (covers tail-overhang too)
                #pragma unroll
                for (int c = 0; c < 8; ++c)
                    #pragma unroll
                    for (int r = 0; r < 4; ++r)
                        if (j*128 + c*16 + quad*4 + r > qt*64 + wq*16 + l16)
                            sacc[c][r] = -1e30f;
            }

            // online softmax (per-lane scalar stats, 2-step cross-quad reduce)
            float mx = -1e30f;
            #pragma unroll
            for (int c = 0; c < 8; ++c)
                #pragma unroll
                for (int r = 0; r < 4; ++r) mx = fmaxf(mx, sacc[c][r]);
            mx = fmaxf(mx, __shfl_xor(mx, 16, 64));
            mx = fmaxf(mx, __shfl_xor(mx, 32, 64));
            float mn = fmaxf(m_run, mx);
            float alpha = __expf(m_run - mn);
            m_run = mn;
            float ls = 0.f;
            #pragma unroll
            for (int c = 0; c < 8; ++c)
                #pragma unroll
                for (int r = 0; r < 4; ++r) {
                    float p = __expf(sacc[c][r] - mn);
                    sacc[c][r] = p;
                    ls += p;
                }
            ls += __shfl_xor(ls, 16, 64);
            ls += __shfl_xor(ls, 32, 64);
            l_run = l_run * alpha + ls;
            #pragma unroll
            for (int c = 0; c < 4; ++c)
                #pragma unroll
                for (int r = 0; r < 4; ++r) oacc[c][r] *= alpha;

            // pack P (truncating v_perm) and build P^T B-frags via bpermute
            unsigned pk[8][2];
            #pragma unroll
            for (int c = 0; c < 8; ++c) {
                pk[c][0] = pack_trunc(sacc[c][1], sacc[c][0]);
                pk[c][1] = pack_trunc(sacc[c][3], sacc[c][2]);
            }
            union { bf16x8 v; int d[4]; } bP[4];
            #pragma unroll
            for (int g = 0; g < 4; ++g)
                #pragma unroll
                for (int jj = 0; jj < 4; ++jj) {
                    int idx = (jj < 2) ? idx01 : idx23;
                    int u = jj & 1;
                    int a0 = __builtin_amdgcn_ds_bpermute(idx, (int)pk[g*2 + 0][u]);
                    int b0 = __builtin_amdgcn_ds_bpermute(idx, (int)pk[g*2 + 1][u]);
                    bP[g].d[jj] = hi ? b0 : a0;
                }

            // O^T += V^T P^T (4 k-chunks of 32)
            #pragma unroll
            for (int c = 0; c < 4; ++c)
                #pragma unroll
                for (int g = 0; g < 4; ++g) {
                    bf16x8 av = *(const bf16x8*)&VTs[buf][c*16 + l16][g*32 + quad*8];
                    oacc[c] = __builtin_amdgcn_mfma_f32_16x16x32_bf16(av, bP[g].v, oacc[c], 0, 0, 0);
                }

            if (j + 1 < n128) {
                #pragma unroll
                for (int a = 0; a < 4; ++a) {
                    *(int4*)&Ks[buf^1][krr][kso + a*8]  = kreg[a];
                    *(int4*)&VTs[buf^1][vrr][vso + a*8] = vreg[a];
                }
            }
            __syncthreads();
        }

        // epilogue: O^T -> O via per-wave LDS scratch (Ks[0]), coalesced 16B stores
        float invl = 1.0f / l_run;
        unsigned short* Wt = &Ks[0][0][0] + wq * (16*72);
        #pragma unroll
        for (int c = 0; c < 4; ++c)
            #pragma unroll
            for (int r = 0; r < 4; ++r)
                Wt[(size_t)l16*72 + c*16 + quad*4 + r] = f2bf(oacc[c][r] * invl);
        __asm__ __volatile__("" ::: "memory");
        #pragma unroll
        for (int p = 0; p < 2; ++p) {
            int row = p*8 + (lane >> 3);
            int d0 = (lane & 7) * 8;
            int4 val = *(const int4*)&Wt[row*72 + d0];
            int tg = qt*64 + wq*16 + row;
            *(int4*)&yatt[((size_t)(b*TSEQ + tg))*CDIM + h*DHEAD + d0] = val;
        }
    }
}

extern "C" void kernel_launch(void* const* d_in, const int* in_sizes, int n_in,
                              void* d_out, int out_size, void* d_ws, size_t ws_size,
                              hipStream_t stream) {
    const float* x   = (const float*)d_in[0];
    const float* Wq  = (const float*)d_in[1];
    const float* Wk  = (const float*)d_in[2];
    const float* Wv  = (const float*)d_in[3];
    const float* Wku = (const float*)d_in[4];
    const float* Wvu = (const float*)d_in[5];
    const float* Wc  = (const float*)d_in[6];

    float* out_y  = (float*)d_out;
    float* out_kl = out_y  + (size_t)MROWS * CDIM;
    float* out_vl = out_kl + (size_t)MROWS * NHEAD*DLAT;

    float* qproj = (float*)d_ws;                                           // 16 MB fp32
    unsigned short* xb   = (unsigned short*)(qproj + (size_t)MROWS*CDIM);  // 8 MB
    unsigned short* qb   = xb  + (size_t)MROWS*CDIM;                       // 8 MB
    unsigned short* kb   = qb  + (size_t)MROWS*CDIM;                       // 8 MB
    unsigned short* vt   = kb  + (size_t)MROWS*CDIM;                       // 8 MB
    unsigned short* wall = vt  + (size_t)MROWS*CDIM;                       // [Wq;Wk;Wv;Wc] 6 MB
    unsigned short* wcb  = wall + (size_t)2048*CDIM;
    unsigned short* yatt = (unsigned short*)qproj;   // alias: qproj dead after latup

    cvt_all<<<(4194304 + 3145728)/1024, 256, 0, stream>>>(x, Wq, Wk, Wv, Wc, xb, wall);

    gemm_proj<<<dim3(2048/128, MROWS/128), 256, 0, stream>>>(
        xb, wall, qproj, out_kl, out_vl, CDIM);

    latup<<<dim3(TSEQ/64, NBATCH*NHEAD), 256, 0, stream>>>(
        qproj, out_kl, out_vl, Wku, Wvu, qb, kb, vt);

    flash_attn<<<dim3(NBATCH*NHEAD, 16), 256, 0, stream>>>(qb, kb, vt, yatt);

    gemm_out<<<dim3(CDIM/128, MROWS/128), 256, 0, stream>>>(yatt, wcb, out_y, CDIM, CDIM);
}

// Round 6
// 277.512 us; speedup vs baseline: 8.3495x; 1.0076x over previous
//
#include <hip/hip_runtime.h>
#include <math.h>

#define NHEAD  16
#define DHEAD  64
#define DLAT   32
#define TSEQ   2048
#define NBATCH 2
#define CDIM   1024
#define MROWS  (NBATCH*TSEQ)   // 4096

typedef __attribute__((ext_vector_type(8))) short bf16x8;
typedef __attribute__((ext_vector_type(4))) float f32x4;

#define AS1 __attribute__((address_space(1)))
#define AS3 __attribute__((address_space(3)))

__device__ __forceinline__ unsigned short f2bf(float f) {
    union { float f; unsigned u; } v; v.f = f;
    unsigned r = v.u + 0x7fff + ((v.u >> 16) & 1);   // RNE
    return (unsigned short)(r >> 16);
}

// pack bf16(lo)|bf16(hi)<<16 by truncation — one v_perm_b32
__device__ __forceinline__ unsigned pack_trunc(float hi, float lo) {
    return __builtin_amdgcn_perm(__float_as_uint(hi), __float_as_uint(lo), 0x07060302u);
}

__device__ __forceinline__ void gld_lds16(const unsigned short* g, unsigned short* l) {
    __builtin_amdgcn_global_load_lds((const AS1 void*)g, (AS3 void*)l, 16, 0, 0);
}

// ---------------- fp32 -> bf16: x and all four weights in ONE launch ----------------
__global__ __launch_bounds__(256) void cvt_all(
        const float* __restrict__ x,  const float* __restrict__ wq,
        const float* __restrict__ wk, const float* __restrict__ wv,
        const float* __restrict__ wc,
        unsigned short* __restrict__ xb, unsigned short* __restrict__ wall) {
    int i = (blockIdx.x * 256 + threadIdx.x) * 4;
    const float* src; unsigned short* dst; int off;
    if      (i < 4194304) { src = x;  dst = xb;             off = 0;       }
    else if (i < 5242880) { src = wq; dst = wall;           off = 4194304; }
    else if (i < 5767168) { src = wk; dst = wall + 1048576; off = 5242880; }
    else if (i < 6291456) { src = wv; dst = wall + 1572864; off = 5767168; }
    else                  { src = wc; dst = wall + 2097152; off = 6291456; }
    float4 v = *(const float4*)(src + (i - off));
    ushort4 o = { f2bf(v.x), f2bf(v.y), f2bf(v.z), f2bf(v.w) };
    *(ushort4*)(dst + (i - off)) = o;
}

// ---------------- MFMA GEMM core: 128x128 tile, BK=32, 4 waves ----------------
__device__ __forceinline__ void gemm_core(
        const unsigned short* __restrict__ A, const unsigned short* __restrict__ W,
        int K, int bm, int bn, unsigned short* As, unsigned short* Bs,
        f32x4 (&acc)[4][4]) {
    const int tid = threadIdx.x;
    const int w = tid >> 6, lane = tid & 63;
    const int quad = lane >> 4, l16 = lane & 15;
    const int wm = (w >> 1) * 64, wn = (w & 1) * 64;

    const int lr = lane >> 2;
    const int le = (lane & 3) * 8;
    const unsigned short* Ag0 = A + (size_t)(bm + w*32 + lr) * K + le;
    const unsigned short* Wg0 = W + (size_t)(bn + w*32 + lr) * K + le;
    unsigned short* AsD0 = &As[(w*32 +  0) * 32];
    unsigned short* AsD1 = &As[(w*32 + 16) * 32];
    unsigned short* BsD0 = &Bs[(w*32 +  0) * 32];
    unsigned short* BsD1 = &Bs[(w*32 + 16) * 32];

    for (int k0 = 0; k0 < K; k0 += 32) {
        gld_lds16(Ag0 + k0,                AsD0);
        gld_lds16(Ag0 + k0 + (size_t)16*K, AsD1);
        gld_lds16(Wg0 + k0,                BsD0);
        gld_lds16(Wg0 + k0 + (size_t)16*K, BsD1);
        __syncthreads();
        bf16x8 af[4], bf[4];
        #pragma unroll
        for (int t = 0; t < 4; ++t)
            af[t] = *(const bf16x8*)&As[(wm + t*16 + l16)*32 + quad*8];
        #pragma unroll
        for (int c = 0; c < 4; ++c)
            bf[c] = *(const bf16x8*)&Bs[(wn + c*16 + l16)*32 + quad*8];
        #pragma unroll
        for (int t = 0; t < 4; ++t)
            #pragma unroll
            for (int c = 0; c < 4; ++c)
                acc[t][c] = __builtin_amdgcn_mfma_f32_16x16x32_bf16(af[t], bf[c], acc[t][c], 0, 0, 0);
        __syncthreads();
    }
}

__global__ __launch_bounds__(256) void gemm_proj(
        const unsigned short* __restrict__ A, const unsigned short* __restrict__ W,
        float* __restrict__ qproj, float* __restrict__ okl, float* __restrict__ ovl,
        int K) {
    __shared__ unsigned short As[128*32];
    __shared__ unsigned short Bs[128*32];
    const int bm = blockIdx.y * 128, bn = blockIdx.x * 128;
    f32x4 acc[4][4] = {};
    gemm_core(A, W, K, bm, bn, As, Bs, acc);

    const int tid = threadIdx.x;
    const int w = tid >> 6, lane = tid & 63;
    const int quad = lane >> 4, l16 = lane & 15;
    const int wm = (w >> 1) * 64, wn = (w & 1) * 64;

    float* base; int ldo;
    if (bn < 1024)      { base = qproj + bn;        ldo = 1024; }
    else if (bn < 1536) { base = okl + (bn - 1024); ldo = 512;  }
    else                { base = ovl + (bn - 1536); ldo = 512;  }

    #pragma unroll
    for (int t = 0; t < 4; ++t)
        #pragma unroll
        for (int c = 0; c < 4; ++c)
            #pragma unroll
            for (int r = 0; r < 4; ++r) {
                int row = bm + wm + t*16 + quad*4 + r;
                int col = wn + c*16 + l16;
                base[(size_t)row * ldo + col] = acc[t][c][r];
            }
}

__global__ __launch_bounds__(256) void gemm_out(
        const unsigned short* __restrict__ A, const unsigned short* __restrict__ W,
        float* __restrict__ O, int N, int K) {
    __shared__ unsigned short As[128*32];
    __shared__ unsigned short Bs[128*32];
    const int bm = blockIdx.y * 128, bn = blockIdx.x * 128;
    f32x4 acc[4][4] = {};
    gemm_core(A, W, K, bm, bn, As, Bs, acc);

    const int tid = threadIdx.x;
    const int w = tid >> 6, lane = tid & 63;
    const int quad = lane >> 4, l16 = lane & 15;
    const int wm = (w >> 1) * 64, wn = (w & 1) * 64;
    #pragma unroll
    for (int t = 0; t < 4; ++t)
        #pragma unroll
        for (int c = 0; c < 4; ++c)
            #pragma unroll
            for (int r = 0; r < 4; ++r) {
                int row = bm + wm + t*16 + quad*4 + r;
                int col = bn + wn + c*16 + l16;
                O[(size_t)row * N + col] = acc[t][c][r];
            }
}

// ---------------- fused latent up-proj (k,v) + q load + RoPE ----------------
__global__ __launch_bounds__(256) void latup(
        const float* __restrict__ qproj, const float* __restrict__ klat,
        const float* __restrict__ vlat,  const float* __restrict__ Wku,
        const float* __restrict__ Wvu,
        unsigned short* __restrict__ qb, unsigned short* __restrict__ kb,
        unsigned short* __restrict__ vt) {
    __shared__ float kls[64][36];
    __shared__ float vls[64][36];
    __shared__ unsigned short vts[64][72];
    const int bh = blockIdx.y, b = bh >> 4, h = bh & 15;
    const int t0 = blockIdx.x * 64;
    const int tid = threadIdx.x;
    {
        const int r = tid >> 2, cs = (tid & 3) * 8;
        const float* ksrc = klat + ((size_t)(b*TSEQ + t0 + r))*(NHEAD*DLAT) + h*DLAT + cs;
        const float* vsrc = vlat + ((size_t)(b*TSEQ + t0 + r))*(NHEAD*DLAT) + h*DLAT + cs;
        *(float4*)&kls[r][cs]   = *(const float4*)ksrc;
        *(float4*)&kls[r][cs+4] = *(const float4*)(ksrc + 4);
        *(float4*)&vls[r][cs]   = *(const float4*)vsrc;
        *(float4*)&vls[r][cs+4] = *(const float4*)(vsrc + 4);
    }
    __syncthreads();
    const int tl = tid & 63;
    const int dg = tid >> 6;
    const int t = t0 + tl;

    float ca[16], sa[16];
    #pragma unroll
    for (int i = 0; i < 16; ++i) {
        int d = dg*16 + i;
        float inv = __expf(-(float)(d & 31) * 0.28782313662425572f);
        __sincosf((float)t * inv, &sa[i], &ca[i]);
    }
    float kl_r[DLAT], vl_r[DLAT];
    #pragma unroll
    for (int l = 0; l < DLAT; ++l) { kl_r[l] = kls[tl][l]; vl_r[l] = vls[tl][l]; }

    float kv[16], vv[16], qv[16];
    #pragma unroll
    for (int i = 0; i < 16; ++i) {
        int d = dg*16 + i;
        float a0 = 0.f, a1 = 0.f;
        #pragma unroll
        for (int l = 0; l < DLAT; ++l) {
            a0 += kl_r[l] * Wku[d*DLAT + l];
            a1 += vl_r[l] * Wvu[d*DLAT + l];
        }
        kv[i] = a0; vv[i] = a1;
    }
    {
        const float* qsrc = qproj + ((size_t)(b*TSEQ + t))*CDIM + h*DHEAD + dg*16;
        #pragma unroll
        for (int i = 0; i < 4; ++i) {
            float4 v4 = *(const float4*)(qsrc + i*4);
            qv[i*4+0]=v4.x; qv[i*4+1]=v4.y; qv[i*4+2]=v4.z; qv[i*4+3]=v4.w;
        }
    }
    unsigned kw[8], qw[8];
    #pragma unroll
    for (int i = 0; i < 8; ++i) {
        int e = 2*i, o = e + 1;
        float ke = kv[e]*ca[e] - kv[o]*sa[e];
        float ko = kv[o]*ca[o] + kv[e]*sa[o];
        float qe = (qv[e]*ca[e] - qv[o]*sa[e]) * 0.125f;
        float qo = (qv[o]*ca[o] + qv[e]*sa[o]) * 0.125f;
        kw[i] = (unsigned)f2bf(ke) | ((unsigned)f2bf(ko) << 16);
        qw[i] = (unsigned)f2bf(qe) | ((unsigned)f2bf(qo) << 16);
    }
    size_t orow = ((size_t)bh*TSEQ + t)*DHEAD + dg*16;
    *(int4*)&kb[orow]     = make_int4(kw[0], kw[1], kw[2], kw[3]);
    *(int4*)&kb[orow + 8] = make_int4(kw[4], kw[5], kw[6], kw[7]);
    *(int4*)&qb[orow]     = make_int4(qw[0], qw[1], qw[2], qw[3]);
    *(int4*)&qb[orow + 8] = make_int4(qw[4], qw[5], qw[6], qw[7]);

    #pragma unroll
    for (int i = 0; i < 16; ++i) vts[dg*16 + i][tl] = f2bf(vv[i]);
    __syncthreads();
    const int r2 = tid >> 2, c2 = (tid & 3) * 16;
    int4 w0 = *(const int4*)&vts[r2][c2];
    int4 w1 = *(const int4*)&vts[r2][c2 + 8];
    unsigned short* vdst = vt + ((size_t)bh*DHEAD + r2)*TSEQ + t0 + c2;
    *(int4*)&vdst[0] = w0;
    *(int4*)&vdst[8] = w1;
}

// ---------------- Flash attention: paired Q-tiles, K-tile=128, no-spill budget ----------------
// __launch_bounds__(256,2): LDS (70KB) caps at 2 blocks/CU anyway; give the register
// allocator the matching budget (~256 VGPR) so the prefetch+softmax state does NOT
// spill to scratch (R5 showed 197MB of HBM spill write-back at VGPR_Count=88).
__global__ __launch_bounds__(256, 2) void flash_attn(
        const unsigned short* __restrict__ qb, const unsigned short* __restrict__ kb,
        const unsigned short* __restrict__ vtb, unsigned short* __restrict__ yatt) {
    const int bh = blockIdx.x;
    const int b = bh >> 4, h = bh & 15;

    __shared__ unsigned short Ks[2][128][72];    // K tile (t,d)
    __shared__ unsigned short VTs[2][64][136];   // V^T tile (d,t)

    const int tid  = threadIdx.x;
    const int wq   = tid >> 6;
    const int lane = tid & 63;
    const int quad = lane >> 4;
    const int l16  = lane & 15;

    const unsigned short* Kbase = kb  + (size_t)bh * TSEQ * DHEAD;
    const unsigned short* Vbase = vtb + (size_t)bh * DHEAD * TSEQ;

    const int krr = tid >> 1, kso = (tid & 1) * 32;
    const int vrr = tid >> 2, vso = (tid & 3) * 32;

    const int idx01 = (((lane >> 4) & 1) * 32 + l16) * 4;
    const int idx23 = idx01 + 64;
    const bool hi = (lane & 32) != 0;

    for (int half = 0; half < 2; ++half) {
        const int qt = half ? (31 - (int)blockIdx.y) : (int)blockIdx.y;
        const int n128 = (qt + 2) >> 1;

        const unsigned short* qbase =
            qb + ((size_t)bh*TSEQ + qt*64 + wq*16 + l16) * DHEAD + quad*8;
        bf16x8 qB0 = *(const bf16x8*)qbase;
        bf16x8 qB1 = *(const bf16x8*)(qbase + 32);

        f32x4 oacc[4] = {};
        float m_run = -1e30f, l_run = 0.f;

        __syncthreads();
        int4 kreg[4], vreg[4];
        #pragma unroll
        for (int a = 0; a < 4; ++a) {
            kreg[a] = *(const int4*)(Kbase + (size_t)krr * DHEAD + kso + a*8);
            vreg[a] = *(const int4*)(Vbase + (size_t)vrr * TSEQ + vso + a*8);
        }
        #pragma unroll
        for (int a = 0; a < 4; ++a) {
            *(int4*)&Ks[0][krr][kso + a*8]  = kreg[a];
            *(int4*)&VTs[0][vrr][vso + a*8] = vreg[a];
        }
        __syncthreads();

        for (int j = 0; j < n128; ++j) {
            const int buf = j & 1;
            if (j + 1 < n128) {
                const int kc = (j + 1) * 128;
                #pragma unroll
                for (int a = 0; a < 4; ++a) {
                    kreg[a] = *(const int4*)(Kbase + (size_t)(kc + krr) * DHEAD + kso + a*8);
                    vreg[a] = *(const int4*)(Vbase + (size_t)vrr * TSEQ + kc + vso + a*8);
                }
            }

            // S^T = K Q^T  (8 chunks of 16 K-rows)
            f32x4 sacc[8];
            #pragma unroll
            for (int c = 0; c < 8; ++c) {
                bf16x8 ak0 = *(const bf16x8*)&Ks[buf][c*16 + l16][quad*8];
                bf16x8 ak1 = *(const bf16x8*)&Ks[buf][c*16 + l16][quad*8 + 32];
                f32x4 z = {0.f, 0.f, 0.f, 0.f};
                z = __builtin_amdgcn_mfma_f32_16x16x32_bf16(ak0, qB0, z, 0, 0, 0);
                z = __builtin_amdgcn_mfma_f32_16x16x32_bf16(ak1, qB1, z, 0, 0, 0);
                sacc[c] = z;
            }
            if (j == n128 - 1) {
                #pragma unroll
                for (int c = 0; c < 8; ++c)
                    #pragma unroll
                    for (int r = 0; r < 4; ++r)
                        if (j*128 + c*16 + quad*4 + r > qt*64 + wq*16 + l16)
                            sacc[c][r] = -1e30f;
            }

            // online softmax
            float mx = -1e30f;
            #pragma unroll
            for (int c = 0; c < 8; ++c)
                #pragma unroll
                for (int r = 0; r < 4; ++r) mx = fmaxf(mx, sacc[c][r]);
            mx = fmaxf(mx, __shfl_xor(mx, 16, 64));
            mx = fmaxf(mx, __shfl_xor(mx, 32, 64));
            float mn = fmaxf(m_run, mx);
            float alpha = __expf(m_run - mn);
            m_run = mn;
            float ls = 0.f;
            #pragma unroll
            for (int c = 0; c < 8; ++c)
                #pragma unroll
                for (int r = 0; r < 4; ++r) {
                    float p = __expf(sacc[c][r] - mn);
                    sacc[c][r] = p;
                    ls += p;
                }
            ls += __shfl_xor(ls, 16, 64);
            ls += __shfl_xor(ls, 32, 64);
            l_run = l_run * alpha + ls;
            #pragma unroll
            for (int c = 0; c < 4; ++c)
                #pragma unroll
                for (int r = 0; r < 4; ++r) oacc[c][r] *= alpha;

            // per-g: pack 2 P-chunks -> bpermute to B-frag -> 4 PV MFMAs.
            // Short live ranges: pack/bP are transient (~8 regs), sacc dies chunk-pair-wise.
            #pragma unroll
            for (int g = 0; g < 4; ++g) {
                unsigned p0a = pack_trunc(sacc[2*g][1],   sacc[2*g][0]);
                unsigned p0b = pack_trunc(sacc[2*g][3],   sacc[2*g][2]);
                unsigned p1a = pack_trunc(sacc[2*g+1][1], sacc[2*g+1][0]);
                unsigned p1b = pack_trunc(sacc[2*g+1][3], sacc[2*g+1][2]);
                union { bf16x8 v; int d[4]; } bP;
                int a0 = __builtin_amdgcn_ds_bpermute(idx01, (int)p0a);
                int b0 = __builtin_amdgcn_ds_bpermute(idx01, (int)p1a);
                bP.d[0] = hi ? b0 : a0;
                int a1 = __builtin_amdgcn_ds_bpermute(idx01, (int)p0b);
                int b1 = __builtin_amdgcn_ds_bpermute(idx01, (int)p1b);
                bP.d[1] = hi ? b1 : a1;
                int a2 = __builtin_amdgcn_ds_bpermute(idx23, (int)p0a);
                int b2 = __builtin_amdgcn_ds_bpermute(idx23, (int)p1a);
                bP.d[2] = hi ? b2 : a2;
                int a3 = __builtin_amdgcn_ds_bpermute(idx23, (int)p0b);
                int b3 = __builtin_amdgcn_ds_bpermute(idx23, (int)p1b);
                bP.d[3] = hi ? b3 : a3;
                #pragma unroll
                for (int c = 0; c < 4; ++c) {
                    bf16x8 av = *(const bf16x8*)&VTs[buf][c*16 + l16][g*32 + quad*8];
                    oacc[c] = __builtin_amdgcn_mfma_f32_16x16x32_bf16(av, bP.v, oacc[c], 0, 0, 0);
                }
            }

            if (j + 1 < n128) {
                #pragma unroll
                for (int a = 0; a < 4; ++a) {
                    *(int4*)&Ks[buf^1][krr][kso + a*8]  = kreg[a];
                    *(int4*)&VTs[buf^1][vrr][vso + a*8] = vreg[a];
                }
            }
            __syncthreads();
        }

        // epilogue: O^T -> O via per-wave LDS scratch, coalesced 16B stores
        float invl = 1.0f / l_run;
        unsigned short* Wt = &Ks[0][0][0] + wq * (16*72);
        #pragma unroll
        for (int c = 0; c < 4; ++c)
            #pragma unroll
            for (int r = 0; r < 4; ++r)
                Wt[(size_t)l16*72 + c*16 + quad*4 + r] = f2bf(oacc[c][r] * invl);
        __asm__ __volatile__("" ::: "memory");
        #pragma unroll
        for (int p = 0; p < 2; ++p) {
            int row = p*8 + (lane >> 3);
            int d0 = (lane & 7) * 8;
            int4 val = *(const int4*)&Wt[row*72 + d0];
            int tg = qt*64 + wq*16 + row;
            *(int4*)&yatt[((size_t)(b*TSEQ + tg))*CDIM + h*DHEAD + d0] = val;
        }
    }
}

extern "C" void kernel_launch(void* const* d_in, const int* in_sizes, int n_in,
                              void* d_out, int out_size, void* d_ws, size_t ws_size,
                              hipStream_t stream) {
    const float* x   = (const float*)d_in[0];
    const float* Wq  = (const float*)d_in[1];
    const float* Wk  = (const float*)d_in[2];
    const float* Wv  = (const float*)d_in[3];
    const float* Wku = (const float*)d_in[4];
    const float* Wvu = (const float*)d_in[5];
    const float* Wc  = (const float*)d_in[6];

    float* out_y  = (float*)d_out;
    float* out_kl = out_y  + (size_t)MROWS * CDIM;
    float* out_vl = out_kl + (size_t)MROWS * NHEAD*DLAT;

    float* qproj = (float*)d_ws;                                           // 16 MB fp32
    unsigned short* xb   = (unsigned short*)(qproj + (size_t)MROWS*CDIM);  // 8 MB
    unsigned short* qb   = xb  + (size_t)MROWS*CDIM;                       // 8 MB
    unsigned short* kb   = qb  + (size_t)MROWS*CDIM;                       // 8 MB
    unsigned short* vt   = kb  + (size_t)MROWS*CDIM;                       // 8 MB
    unsigned short* wall = vt  + (size_t)MROWS*CDIM;                       // [Wq;Wk;Wv;Wc] 6 MB
    unsigned short* wcb  = wall + (size_t)2048*CDIM;
    unsigned short* yatt = (unsigned short*)qproj;   // alias: qproj dead after latup

    cvt_all<<<(4194304 + 3145728)/1024, 256, 0, stream>>>(x, Wq, Wk, Wv, Wc, xb, wall);

    gemm_proj<<<dim3(2048/128, MROWS/128), 256, 0, stream>>>(
        xb, wall, qproj, out_kl, out_vl, CDIM);

    latup<<<dim3(TSEQ/64, NBATCH*NHEAD), 256, 0, stream>>>(
        qproj, out_kl, out_vl, Wku, Wvu, qb, kb, vt);

    flash_attn<<<dim3(NBATCH*NHEAD, 16), 256, 0, stream>>>(qb, kb, vt, yatt);

    gemm_out<<<dim3(CDIM/128, MROWS/128), 256, 0, stream>>>(yatt, wcb, out_y, CDIM, CDIM);
}

// Round 7
// 231.583 us; speedup vs baseline: 10.0054x; 1.1983x over previous
//
#include <hip/hip_runtime.h>
#include <math.h>

#define NHEAD  16
#define DHEAD  64
#define DLAT   32
#define TSEQ   2048
#define NBATCH 2
#define CDIM   1024
#define MROWS  (NBATCH*TSEQ)   // 4096

typedef __attribute__((ext_vector_type(8))) short bf16x8;
typedef __attribute__((ext_vector_type(4))) float f32x4;

#define AS1 __attribute__((address_space(1)))
#define AS3 __attribute__((address_space(3)))

__device__ __forceinline__ unsigned short f2bf(float f) {
    union { float f; unsigned u; } v; v.f = f;
    unsigned r = v.u + 0x7fff + ((v.u >> 16) & 1);   // RNE
    return (unsigned short)(r >> 16);
}

// pack bf16(lo)|bf16(hi)<<16 by truncation — one v_perm_b32
__device__ __forceinline__ unsigned pack_trunc(float hi, float lo) {
    return __builtin_amdgcn_perm(__float_as_uint(hi), __float_as_uint(lo), 0x07060302u);
}

__device__ __forceinline__ void gld_lds16(const unsigned short* g, unsigned short* l) {
    __builtin_amdgcn_global_load_lds((const AS1 void*)g, (AS3 void*)l, 16, 0, 0);
}

// ---------------- fp32 -> bf16: x and all four weights in ONE launch ----------------
__global__ __launch_bounds__(256) void cvt_all(
        const float* __restrict__ x,  const float* __restrict__ wq,
        const float* __restrict__ wk, const float* __restrict__ wv,
        const float* __restrict__ wc,
        unsigned short* __restrict__ xb, unsigned short* __restrict__ wall) {
    int i = (blockIdx.x * 256 + threadIdx.x) * 4;
    const float* src; unsigned short* dst; int off;
    if      (i < 4194304) { src = x;  dst = xb;             off = 0;       }
    else if (i < 5242880) { src = wq; dst = wall;           off = 4194304; }
    else if (i < 5767168) { src = wk; dst = wall + 1048576; off = 5242880; }
    else if (i < 6291456) { src = wv; dst = wall + 1572864; off = 5767168; }
    else                  { src = wc; dst = wall + 2097152; off = 6291456; }
    float4 v = *(const float4*)(src + (i - off));
    ushort4 o = { f2bf(v.x), f2bf(v.y), f2bf(v.z), f2bf(v.w) };
    *(ushort4*)(dst + (i - off)) = o;
}

// ---------------- MFMA GEMM core: 128x128 tile, BK=32, 4 waves ----------------
__device__ __forceinline__ void gemm_core(
        const unsigned short* __restrict__ A, const unsigned short* __restrict__ W,
        int K, int bm, int bn, unsigned short* As, unsigned short* Bs,
        f32x4 (&acc)[4][4]) {
    const int tid = threadIdx.x;
    const int w = tid >> 6, lane = tid & 63;
    const int quad = lane >> 4, l16 = lane & 15;
    const int wm = (w >> 1) * 64, wn = (w & 1) * 64;

    const int lr = lane >> 2;
    const int le = (lane & 3) * 8;
    const unsigned short* Ag0 = A + (size_t)(bm + w*32 + lr) * K + le;
    const unsigned short* Wg0 = W + (size_t)(bn + w*32 + lr) * K + le;
    unsigned short* AsD0 = &As[(w*32 +  0) * 32];
    unsigned short* AsD1 = &As[(w*32 + 16) * 32];
    unsigned short* BsD0 = &Bs[(w*32 +  0) * 32];
    unsigned short* BsD1 = &Bs[(w*32 + 16) * 32];

    for (int k0 = 0; k0 < K; k0 += 32) {
        gld_lds16(Ag0 + k0,                AsD0);
        gld_lds16(Ag0 + k0 + (size_t)16*K, AsD1);
        gld_lds16(Wg0 + k0,                BsD0);
        gld_lds16(Wg0 + k0 + (size_t)16*K, BsD1);
        __syncthreads();
        bf16x8 af[4], bf[4];
        #pragma unroll
        for (int t = 0; t < 4; ++t)
            af[t] = *(const bf16x8*)&As[(wm + t*16 + l16)*32 + quad*8];
        #pragma unroll
        for (int c = 0; c < 4; ++c)
            bf[c] = *(const bf16x8*)&Bs[(wn + c*16 + l16)*32 + quad*8];
        #pragma unroll
        for (int t = 0; t < 4; ++t)
            #pragma unroll
            for (int c = 0; c < 4; ++c)
                acc[t][c] = __builtin_amdgcn_mfma_f32_16x16x32_bf16(af[t], bf[c], acc[t][c], 0, 0, 0);
        __syncthreads();
    }
}

__global__ __launch_bounds__(256) void gemm_proj(
        const unsigned short* __restrict__ A, const unsigned short* __restrict__ W,
        float* __restrict__ qproj, float* __restrict__ okl, float* __restrict__ ovl,
        int K) {
    __shared__ unsigned short As[128*32];
    __shared__ unsigned short Bs[128*32];
    const int bm = blockIdx.y * 128, bn = blockIdx.x * 128;
    f32x4 acc[4][4] = {};
    gemm_core(A, W, K, bm, bn, As, Bs, acc);

    const int tid = threadIdx.x;
    const int w = tid >> 6, lane = tid & 63;
    const int quad = lane >> 4, l16 = lane & 15;
    const int wm = (w >> 1) * 64, wn = (w & 1) * 64;

    float* base; int ldo;
    if (bn < 1024)      { base = qproj + bn;        ldo = 1024; }
    else if (bn < 1536) { base = okl + (bn - 1024); ldo = 512;  }
    else                { base = ovl + (bn - 1536); ldo = 512;  }

    #pragma unroll
    for (int t = 0; t < 4; ++t)
        #pragma unroll
        for (int c = 0; c < 4; ++c)
            #pragma unroll
            for (int r = 0; r < 4; ++r) {
                int row = bm + wm + t*16 + quad*4 + r;
                int col = wn + c*16 + l16;
                base[(size_t)row * ldo + col] = acc[t][c][r];
            }
}

__global__ __launch_bounds__(256) void gemm_out(
        const unsigned short* __restrict__ A, const unsigned short* __restrict__ W,
        float* __restrict__ O, int N, int K) {
    __shared__ unsigned short As[128*32];
    __shared__ unsigned short Bs[128*32];
    const int bm = blockIdx.y * 128, bn = blockIdx.x * 128;
    f32x4 acc[4][4] = {};
    gemm_core(A, W, K, bm, bn, As, Bs, acc);

    const int tid = threadIdx.x;
    const int w = tid >> 6, lane = tid & 63;
    const int quad = lane >> 4, l16 = lane & 15;
    const int wm = (w >> 1) * 64, wn = (w & 1) * 64;
    #pragma unroll
    for (int t = 0; t < 4; ++t)
        #pragma unroll
        for (int c = 0; c < 4; ++c)
            #pragma unroll
            for (int r = 0; r < 4; ++r) {
                int row = bm + wm + t*16 + quad*4 + r;
                int col = bn + wn + c*16 + l16;
                O[(size_t)row * N + col] = acc[t][c][r];
            }
}

// ---------------- fused latent up-proj (k,v) + q load + RoPE ----------------
__global__ __launch_bounds__(256) void latup(
        const float* __restrict__ qproj, const float* __restrict__ klat,
        const float* __restrict__ vlat,  const float* __restrict__ Wku,
        const float* __restrict__ Wvu,
        unsigned short* __restrict__ qb, unsigned short* __restrict__ kb,
        unsigned short* __restrict__ vt) {
    __shared__ float kls[64][36];
    __shared__ float vls[64][36];
    __shared__ unsigned short vts[64][72];
    const int bh = blockIdx.y, b = bh >> 4, h = bh & 15;
    const int t0 = blockIdx.x * 64;
    const int tid = threadIdx.x;
    {
        const int r = tid >> 2, cs = (tid & 3) * 8;
        const float* ksrc = klat + ((size_t)(b*TSEQ + t0 + r))*(NHEAD*DLAT) + h*DLAT + cs;
        const float* vsrc = vlat + ((size_t)(b*TSEQ + t0 + r))*(NHEAD*DLAT) + h*DLAT + cs;
        *(float4*)&kls[r][cs]   = *(const float4*)ksrc;
        *(float4*)&kls[r][cs+4] = *(const float4*)(ksrc + 4);
        *(float4*)&vls[r][cs]   = *(const float4*)vsrc;
        *(float4*)&vls[r][cs+4] = *(const float4*)(vsrc + 4);
    }
    __syncthreads();
    const int tl = tid & 63;
    const int dg = tid >> 6;
    const int t = t0 + tl;

    float ca[16], sa[16];
    #pragma unroll
    for (int i = 0; i < 16; ++i) {
        int d = dg*16 + i;
        float inv = __expf(-(float)(d & 31) * 0.28782313662425572f);
        __sincosf((float)t * inv, &sa[i], &ca[i]);
    }
    float kl_r[DLAT], vl_r[DLAT];
    #pragma unroll
    for (int l = 0; l < DLAT; ++l) { kl_r[l] = kls[tl][l]; vl_r[l] = vls[tl][l]; }

    float kv[16], vv[16], qv[16];
    #pragma unroll
    for (int i = 0; i < 16; ++i) {
        int d = dg*16 + i;
        float a0 = 0.f, a1 = 0.f;
        #pragma unroll
        for (int l = 0; l < DLAT; ++l) {
            a0 += kl_r[l] * Wku[d*DLAT + l];
            a1 += vl_r[l] * Wvu[d*DLAT + l];
        }
        kv[i] = a0; vv[i] = a1;
    }
    {
        const float* qsrc = qproj + ((size_t)(b*TSEQ + t))*CDIM + h*DHEAD + dg*16;
        #pragma unroll
        for (int i = 0; i < 4; ++i) {
            float4 v4 = *(const float4*)(qsrc + i*4);
            qv[i*4+0]=v4.x; qv[i*4+1]=v4.y; qv[i*4+2]=v4.z; qv[i*4+3]=v4.w;
        }
    }
    unsigned kw[8], qw[8];
    #pragma unroll
    for (int i = 0; i < 8; ++i) {
        int e = 2*i, o = e + 1;
        float ke = kv[e]*ca[e] - kv[o]*sa[e];
        float ko = kv[o]*ca[o] + kv[e]*sa[o];
        float qe = (qv[e]*ca[e] - qv[o]*sa[e]) * 0.125f;
        float qo = (qv[o]*ca[o] + qv[e]*sa[o]) * 0.125f;
        kw[i] = (unsigned)f2bf(ke) | ((unsigned)f2bf(ko) << 16);
        qw[i] = (unsigned)f2bf(qe) | ((unsigned)f2bf(qo) << 16);
    }
    size_t orow = ((size_t)bh*TSEQ + t)*DHEAD + dg*16;
    *(int4*)&kb[orow]     = make_int4(kw[0], kw[1], kw[2], kw[3]);
    *(int4*)&kb[orow + 8] = make_int4(kw[4], kw[5], kw[6], kw[7]);
    *(int4*)&qb[orow]     = make_int4(qw[0], qw[1], qw[2], qw[3]);
    *(int4*)&qb[orow + 8] = make_int4(qw[4], qw[5], qw[6], qw[7]);

    #pragma unroll
    for (int i = 0; i < 16; ++i) vts[dg*16 + i][tl] = f2bf(vv[i]);
    __syncthreads();
    const int r2 = tid >> 2, c2 = (tid & 3) * 16;
    int4 w0 = *(const int4*)&vts[r2][c2];
    int4 w1 = *(const int4*)&vts[r2][c2 + 8];
    unsigned short* vdst = vt + ((size_t)bh*DHEAD + r2)*TSEQ + t0 + c2;
    *(int4*)&vdst[0] = w0;
    *(int4*)&vdst[8] = w1;
}

// ---------------- Flash attention: gld_lds DMA staging, XOR-swizzled LDS, no spills ----------------
// R6 post-mortem: 193 MB/dispatch of scratch spill writes (kreg/vreg prefetch state).
// Fix: K/V staged by global_load_lds (zero register footprint). gld_lds forces
// dest = wave-uniform base + lane*16 (no padding), so tiles are unpadded with an
// XOR bank swizzle applied on the per-lane *source* address:
//   K  [128][64]: phys col16 = log col16 ^ (row & 7)
//   V^T[64][128]: phys col16 = log col16 ^ (row & 15)
__global__ __launch_bounds__(256, 2) void flash_attn(
        const unsigned short* __restrict__ qb, const unsigned short* __restrict__ kb,
        const unsigned short* __restrict__ vtb, unsigned short* __restrict__ yatt) {
    const int bh = blockIdx.x;
    const int b = bh >> 4, h = bh & 15;

    __shared__ unsigned short Ks[2][128][64];    // 32 KB
    __shared__ unsigned short VTs[2][64][128];   // 32 KB

    const int tid  = threadIdx.x;
    const int wq   = tid >> 6;
    const int lane = tid & 63;
    const int quad = lane >> 4;
    const int l16  = lane & 15;

    const unsigned short* Kbase = kb  + (size_t)bh * TSEQ * DHEAD;
    const unsigned short* Vbase = vtb + (size_t)bh * DHEAD * TSEQ;

    // DMA source lane-mapping (swizzled)
    const int kr8 = lane >> 3, kcp = lane & 7;
    const int kcl = (kcp ^ kr8) * 8;              // K logical elem offset in row
    const int vr4 = lane >> 4, vcp = lane & 15;

    // swizzled MFMA read offsets
    const int kx0 = (quad ^ (l16 & 7)) * 8;
    const int kx1 = ((quad + 4) ^ (l16 & 7)) * 8;

    const int idx01 = (((lane >> 4) & 1) * 32 + l16) * 4;
    const int idx23 = idx01 + 64;
    const bool hi = (lane & 32) != 0;

    for (int half = 0; half < 2; ++half) {
        const int qt = half ? (31 - (int)blockIdx.y) : (int)blockIdx.y;
        const int n128 = (qt + 2) >> 1;

        const unsigned short* qbase =
            qb + ((size_t)bh*TSEQ + qt*64 + wq*16 + l16) * DHEAD + quad*8;
        bf16x8 qB0 = *(const bf16x8*)qbase;
        bf16x8 qB1 = *(const bf16x8*)(qbase + 32);

        f32x4 oacc[4] = {};
        float m_run = -1e30f, l_run = 0.f;

        __syncthreads();   // prev half's epilogue LDS reads done before DMA overwrites
        #pragma unroll
        for (int i = 0; i < 4; ++i) {   // preload tile 0 into buf 0
            gld_lds16(Kbase + (size_t)(wq*32 + i*8 + kr8)*DHEAD + kcl,
                      &Ks[0][wq*32 + i*8][0]);
            int vcl = (vcp ^ ((i*4 + vr4) & 15)) * 8;
            gld_lds16(Vbase + (size_t)(wq*16 + i*4 + vr4)*TSEQ + vcl,
                      &VTs[0][wq*16 + i*4][0]);
        }
        __syncthreads();

        for (int j = 0; j < n128; ++j) {
            const int buf = j & 1;
            if (j + 1 < n128) {   // async DMA prefetch of next tile into buf^1
                const int kc = (j + 1) * 128;
                #pragma unroll
                for (int i = 0; i < 4; ++i) {
                    gld_lds16(Kbase + (size_t)(kc + wq*32 + i*8 + kr8)*DHEAD + kcl,
                              &Ks[buf^1][wq*32 + i*8][0]);
                    int vcl = (vcp ^ ((i*4 + vr4) & 15)) * 8;
                    gld_lds16(Vbase + (size_t)(wq*16 + i*4 + vr4)*TSEQ + kc + vcl,
                              &VTs[buf^1][wq*16 + i*4][0]);
                }
            }

            // S^T = K Q^T  (8 chunks of 16 K-rows)
            f32x4 sacc[8];
            #pragma unroll
            for (int c = 0; c < 8; ++c) {
                bf16x8 ak0 = *(const bf16x8*)&Ks[buf][c*16 + l16][kx0];
                bf16x8 ak1 = *(const bf16x8*)&Ks[buf][c*16 + l16][kx1];
                f32x4 z = {0.f, 0.f, 0.f, 0.f};
                z = __builtin_amdgcn_mfma_f32_16x16x32_bf16(ak0, qB0, z, 0, 0, 0);
                z = __builtin_amdgcn_mfma_f32_16x16x32_bf16(ak1, qB1, z, 0, 0, 0);
                sacc[c] = z;
            }
            if (j == n128 - 1) {   // causal mask (covers the 128-overhang too)
                #pragma unroll
                for (int c = 0; c < 8; ++c)
                    #pragma unroll
                    for (int r = 0; r < 4; ++r)
                        if (j*128 + c*16 + quad*4 + r > qt*64 + wq*16 + l16)
                            sacc[c][r] = -1e30f;
            }

            // online softmax (per-lane scalar stats, 2-step cross-quad reduce)
            float mx = -1e30f;
            #pragma unroll
            for (int c = 0; c < 8; ++c)
                #pragma unroll
                for (int r = 0; r < 4; ++r) mx = fmaxf(mx, sacc[c][r]);
            mx = fmaxf(mx, __shfl_xor(mx, 16, 64));
            mx = fmaxf(mx, __shfl_xor(mx, 32, 64));
            float mn = fmaxf(m_run, mx);
            float alpha = __expf(m_run - mn);
            m_run = mn;
            float ls = 0.f;
            #pragma unroll
            for (int c = 0; c < 8; ++c)
                #pragma unroll
                for (int r = 0; r < 4; ++r) {
                    float p = __expf(sacc[c][r] - mn);
                    sacc[c][r] = p;
                    ls += p;
                }
            ls += __shfl_xor(ls, 16, 64);
            ls += __shfl_xor(ls, 32, 64);
            l_run = l_run * alpha + ls;
            #pragma unroll
            for (int c = 0; c < 4; ++c)
                #pragma unroll
                for (int r = 0; r < 4; ++r) oacc[c][r] *= alpha;

            // per-g: pack 2 P-chunks -> bpermute to B-frag -> 4 PV MFMAs
            #pragma unroll
            for (int g = 0; g < 4; ++g) {
                unsigned p0a = pack_trunc(sacc[2*g][1],   sacc[2*g][0]);
                unsigned p0b = pack_trunc(sacc[2*g][3],   sacc[2*g][2]);
                unsigned p1a = pack_trunc(sacc[2*g+1][1], sacc[2*g+1][0]);
                unsigned p1b = pack_trunc(sacc[2*g+1][3], sacc[2*g+1][2]);
                union { bf16x8 v; int d[4]; } bP;
                int a0 = __builtin_amdgcn_ds_bpermute(idx01, (int)p0a);
                int b0 = __builtin_amdgcn_ds_bpermute(idx01, (int)p1a);
                bP.d[0] = hi ? b0 : a0;
                int a1 = __builtin_amdgcn_ds_bpermute(idx01, (int)p0b);
                int b1 = __builtin_amdgcn_ds_bpermute(idx01, (int)p1b);
                bP.d[1] = hi ? b1 : a1;
                int a2 = __builtin_amdgcn_ds_bpermute(idx23, (int)p0a);
                int b2 = __builtin_amdgcn_ds_bpermute(idx23, (int)p1a);
                bP.d[2] = hi ? b2 : a2;
                int a3 = __builtin_amdgcn_ds_bpermute(idx23, (int)p0b);
                int b3 = __builtin_amdgcn_ds_bpermute(idx23, (int)p1b);
                bP.d[3] = hi ? b3 : a3;
                #pragma unroll
                for (int c = 0; c < 4; ++c) {
                    bf16x8 av = *(const bf16x8*)&VTs[buf][c*16 + l16][((g*4 + quad) ^ l16) * 8];
                    oacc[c] = __builtin_amdgcn_mfma_f32_16x16x32_bf16(av, bP.v, oacc[c], 0, 0, 0);
                }
            }

            __syncthreads();   // drains prefetch DMA + protects buf reuse
        }

        // epilogue: O^T -> O via per-wave LDS scratch (stride 72), coalesced 16B stores
        float invl = 1.0f / l_run;
        unsigned short* Wt = &Ks[0][0][0] + wq * (16*72);
        #pragma unroll
        for (int c = 0; c < 4; ++c)
            #pragma unroll
            for (int r = 0; r < 4; ++r)
                Wt[(size_t)l16*72 + c*16 + quad*4 + r] = f2bf(oacc[c][r] * invl);
        __asm__ __volatile__("" ::: "memory");
        #pragma unroll
        for (int p = 0; p < 2; ++p) {
            int row = p*8 + (lane >> 3);
            int d0 = (lane & 7) * 8;
            int4 val = *(const int4*)&Wt[row*72 + d0];
            int tg = qt*64 + wq*16 + row;
            *(int4*)&yatt[((size_t)(b*TSEQ + tg))*CDIM + h*DHEAD + d0] = val;
        }
    }
}

extern "C" void kernel_launch(void* const* d_in, const int* in_sizes, int n_in,
                              void* d_out, int out_size, void* d_ws, size_t ws_size,
                              hipStream_t stream) {
    const float* x   = (const float*)d_in[0];
    const float* Wq  = (const float*)d_in[1];
    const float* Wk  = (const float*)d_in[2];
    const float* Wv  = (const float*)d_in[3];
    const float* Wku = (const float*)d_in[4];
    const float* Wvu = (const float*)d_in[5];
    const float* Wc  = (const float*)d_in[6];

    float* out_y  = (float*)d_out;
    float* out_kl = out_y  + (size_t)MROWS * CDIM;
    float* out_vl = out_kl + (size_t)MROWS * NHEAD*DLAT;

    float* qproj = (float*)d_ws;                                           // 16 MB fp32
    unsigned short* xb   = (unsigned short*)(qproj + (size_t)MROWS*CDIM);  // 8 MB
    unsigned short* qb   = xb  + (size_t)MROWS*CDIM;                       // 8 MB
    unsigned short* kb   = qb  + (size_t)MROWS*CDIM;                       // 8 MB
    unsigned short* vt   = kb  + (size_t)MROWS*CDIM;                       // 8 MB
    unsigned short* wall = vt  + (size_t)MROWS*CDIM;                       // [Wq;Wk;Wv;Wc] 6 MB
    unsigned short* wcb  = wall + (size_t)2048*CDIM;
    unsigned short* yatt = (unsigned short*)qproj;   // alias: qproj dead after latup

    cvt_all<<<(4194304 + 3145728)/1024, 256, 0, stream>>>(x, Wq, Wk, Wv, Wc, xb, wall);

    gemm_proj<<<dim3(2048/128, MROWS/128), 256, 0, stream>>>(
        xb, wall, qproj, out_kl, out_vl, CDIM);

    latup<<<dim3(TSEQ/64, NBATCH*NHEAD), 256, 0, stream>>>(
        qproj, out_kl, out_vl, Wku, Wvu, qb, kb, vt);

    flash_attn<<<dim3(NBATCH*NHEAD, 16), 256, 0, stream>>>(qb, kb, vt, yatt);

    gemm_out<<<dim3(CDIM/128, MROWS/128), 256, 0, stream>>>(yatt, wcb, out_y, CDIM, CDIM);
}